// Round 6
// baseline (561.524 us; speedup 1.0000x reference)
//
#include <hip/hip_runtime.h>
#include <hip/hip_bf16.h>

#define D 64
#define NRAT 6

typedef float f32x4 __attribute__((ext_vector_type(4)));
typedef short bf16x8 __attribute__((ext_vector_type(8)));
typedef short s16x4 __attribute__((ext_vector_type(4)));

union FragU { uint32_t u[4]; bf16x8 v; };
union Frag8 { s16x4 h[2]; bf16x8 v; };

__device__ __forceinline__ short f2bf(float f) {
    __hip_bfloat16 h = __float2bfloat16(f);
    union { __hip_bfloat16 h; short s; } c; c.h = h; return c.s;
}
__device__ __forceinline__ uint32_t pk2(float a, float b) {
    union { short s[2]; uint32_t u; } c; c.s[0] = f2bf(a); c.s[1] = f2bf(b); return c.u;
}

// hu[n] = bf16(user_emb[user_ids[n]] + gender_emb[gender[n]]);  hi analog.
__global__ void build_h(const int* __restrict__ uid, const int* __restrict__ iid,
                        const int* __restrict__ gender, const int* __restrict__ genres,
                        const float* __restrict__ user_emb, const float* __restrict__ item_emb,
                        const float* __restrict__ gender_emb, const float* __restrict__ genre_emb,
                        unsigned short* __restrict__ hu, unsigned short* __restrict__ hi,
                        int NU, int NI) {
    int t = blockIdx.x * blockDim.x + threadIdx.x;
    int total = (NU + NI) * 16;            // one float4 (4 dims) per thread
    if (t >= total) return;
    int row = t >> 4, c = t & 15;
    uint2 o;
    if (row < NU) {
        int u = uid[row], g = gender[row];
        float4 a = ((const float4*)user_emb)[(size_t)u * 16 + c];
        float4 b = ((const float4*)gender_emb)[(size_t)g * 16 + c];
        o.x = pk2(a.x + b.x, a.y + b.y); o.y = pk2(a.z + b.z, a.w + b.w);
        ((uint2*)hu)[(size_t)row * 16 + c] = o;
    } else {
        int r2 = row - NU;
        int it = iid[r2], ge = genres[r2];
        float4 a = ((const float4*)item_emb)[(size_t)it * 16 + c];
        float4 b = ((const float4*)genre_emb)[(size_t)ge * 16 + c];
        o.x = pk2(a.x + b.x, a.y + b.y); o.y = pk2(a.z + b.z, a.w + b.w);
        ((uint2*)hi)[(size_t)r2 * 16 + c] = o;
    }
}

// Coarse histogram over dst>>shift (<=256 buckets), LDS-aggregated.
__global__ __launch_bounds__(256) void coarse_hist(const int* __restrict__ dst,
                                                   int* __restrict__ cnt, int E, int shift) {
    __shared__ int h[256];
    h[threadIdx.x] = 0; __syncthreads();
    for (int i = blockIdx.x * blockDim.x + threadIdx.x; i < E; i += gridDim.x * blockDim.x)
        atomicAdd(&h[dst[i] >> shift], 1);
    __syncthreads();
    int v = h[threadIdx.x];
    if (v) atomicAdd(&cnt[threadIdx.x], v);
}

// 1-block exclusive scan of <=256 coarse counts -> coarseOff (+total) and cursor copy.
__global__ __launch_bounds__(256) void coarse_scan(const int* __restrict__ cnt,
                                                   int* __restrict__ coarseOff,
                                                   int* __restrict__ coarseCur, int NB, int E) {
    __shared__ int p[256];
    int tid = threadIdx.x;
    int v = (tid < NB) ? cnt[tid] : 0;
    p[tid] = v; __syncthreads();
    for (int dd = 1; dd < 256; dd <<= 1) {
        int a = (tid >= dd) ? p[tid - dd] : 0;
        __syncthreads();
        p[tid] += a;
        __syncthreads();
    }
    int excl = p[tid] - v;
    if (tid < NB) { coarseOff[tid] = excl; coarseCur[tid] = excl; }
    if (tid == 0) coarseOff[NB] = E;
}

// Pass A: coarse-bucket edges. Record = src(17b) | r(3b) | dstLow(<=9b at bit 20).
__global__ __launch_bounds__(256) void multisplit_A(
        const int* __restrict__ dst, const int* __restrict__ src,
        const int* __restrict__ rating, int* __restrict__ coarseCur,
        unsigned* __restrict__ staged, int E, int shift) {
    __shared__ unsigned srt[2048];
    __shared__ int sft[2048];
    __shared__ int hist[256], pfx[256], shm[256];
    const int tid = threadIdx.x;
    const int tile = blockIdx.x * 2048;
    int cnt = E - tile; if (cnt > 2048) cnt = 2048;
    hist[tid] = 0;
    __syncthreads();
    unsigned rec[8]; int bk[8];
    #pragma unroll
    for (int k = 0; k < 8; ++k) {
        int i = tile + k * 256 + tid;
        bk[k] = -1;
        if (i < E) {
            int d = dst[i], s = src[i], r = rating[i];
            bk[k] = d >> shift;
            rec[k] = (unsigned)s | ((unsigned)r << 17) | ((unsigned)(d & ((1 << shift) - 1)) << 20);
            atomicAdd(&hist[bk[k]], 1);
        }
    }
    __syncthreads();
    pfx[tid] = hist[tid];
    __syncthreads();
    for (int dd = 1; dd < 256; dd <<= 1) {
        int a = (tid >= dd) ? pfx[tid - dd] : 0;
        __syncthreads();
        pfx[tid] += a;
        __syncthreads();
    }
    int h = hist[tid];
    int excl = pfx[tid] - h;
    int gb = 0;
    if (h > 0) gb = atomicAdd(&coarseCur[tid], h);
    shm[tid] = gb - excl;
    __syncthreads();
    hist[tid] = excl;          // reuse as local cursor
    __syncthreads();
    #pragma unroll
    for (int k = 0; k < 8; ++k) {
        if (bk[k] >= 0) {
            int p = atomicAdd(&hist[bk[k]], 1);
            srt[p] = rec[k];
            sft[p] = shm[bk[k]];
        }
    }
    __syncthreads();
    for (int i = tid; i < cnt; i += 256)
        staged[sft[i] + i] = srt[i];
}

// Pass B: one block per coarse bucket. LDS-stage records, local 512-slot hist
// + scan -> CSR off[] for this dst range, then in-place sorted write.
__global__ __launch_bounds__(256) void multisplit_B(
        unsigned* __restrict__ staged, const int* __restrict__ coarseOff,
        int* __restrict__ off, int N, int E, int shift) {
    __shared__ unsigned rec[16384];
    __shared__ int hist[512], pfx[512];
    const int tid = threadIdx.x;
    const int b = blockIdx.x;
    const int range = 1 << shift;
    int cbase = coarseOff[b];
    int cnt = coarseOff[b + 1] - cbase;
    if (cnt > 16384) cnt = 16384;   // safety guard (never expected)
    hist[tid] = 0; hist[tid + 256] = 0;
    __syncthreads();
    for (int i = tid; i < cnt; i += 256) {
        unsigned x = staged[cbase + i];
        rec[i] = x;
        atomicAdd(&hist[x >> 20], 1);
    }
    __syncthreads();
    pfx[tid] = hist[tid]; pfx[tid + 256] = hist[tid + 256];
    __syncthreads();
    for (int dd = 1; dd < 256; dd <<= 1) {
        int a = (tid >= dd) ? pfx[tid - dd] : 0;
        int c = (tid >= dd) ? pfx[tid + 256 - dd] : 0;
        __syncthreads();
        pfx[tid] += a; pfx[tid + 256] += c;
        __syncthreads();
    }
    int tot0 = pfx[255];
    __syncthreads();
    pfx[tid + 256] += tot0;
    __syncthreads();
    int e0 = pfx[tid] - hist[tid];
    int e1 = pfx[tid + 256] - hist[tid + 256];
    __syncthreads();
    hist[tid] = e0; hist[tid + 256] = e1;   // cursors
    int dbase = b << shift;
    if (dbase + tid < N) off[dbase + tid] = cbase + e0;
    if (range > 256 && dbase + tid + 256 < N) off[dbase + tid + 256] = cbase + e1;
    if (b == gridDim.x - 1 && tid == 0) off[N] = E;
    __syncthreads();
    for (int i = tid; i < cnt; i += 256) {
        unsigned x = rec[i];
        int p = atomicAdd(&hist[x >> 20], 1);
        staged[cbase + p] = x;
    }
}

// One-time: pack weights (bf16) into MFMA fragment order.
__global__ void prep_weights(const float* __restrict__ Wr_w, const float* __restrict__ Wr_wb,
                             const float* __restrict__ Ww, const float* __restrict__ Wwb,
                             const float* __restrict__ Vf, const float* __restrict__ Wf,
                             short* __restrict__ pWrW, short* __restrict__ pWrWB,
                             short* __restrict__ pWw, short* __restrict__ pWwb,
                             short* __restrict__ pVf, short* __restrict__ pWf) {
    int t = blockIdx.x * blockDim.x + threadIdx.x;
    const float* src; short* dst; int K; int idx;
    if      (t < 24576) { src = Wr_w;  dst = pWrW;  K = 64;  idx = t; }
    else if (t < 49152) { src = Wr_wb; dst = pWrWB; K = 64;  idx = t - 24576; }
    else if (t < 57344) { src = Ww;    dst = pWw;   K = 128; idx = t - 49152; }
    else if (t < 65536) { src = Wwb;   dst = pWwb;  K = 128; idx = t - 57344; }
    else if (t < 69632) { src = Vf;    dst = pVf;   K = 64;  idx = t - 65536; }
    else if (t < 73728) { src = Wf;    dst = pWf;   K = 64;  idx = t - 69632; }
    else return;
    int per  = 64 * K;
    int sub  = idx / per;            // r for Wr packs, 0 otherwise
    int li   = idx % per;
    int e    = li & 7;
    int lane = (li >> 3) & 63;
    int frag = li >> 9;              // t16*(K/32) + tk
    int nkt  = K >> 5;
    int t16  = frag / nkt, tk = frag % nkt;
    int row  = t16 * 16 + (lane & 15);
    int col  = tk * 32 + (lane >> 4) * 8 + e;
    dst[idx] = f2bf(src[((size_t)(sub * 64 + row)) * K + col]);
}

// Fused gather + transform. 4 waves/block, 64 nodes/block, 16 nodes/wave.
// Phase 1 (per wave): gather-sum bf16 h_src rows per rating into f32 regs,
// store bf16 S-tile into per-wave LDS (no HBM S).
// Phase 2 (per wave): 3-GEMM MFMA transform reading S from LDS, hd bf16.
__global__ __launch_bounds__(256) void fused_gt(
        const int* __restrict__ off, const unsigned* __restrict__ packed,
        const unsigned short* __restrict__ h_src,   // [Nsrc][64] bf16
        const unsigned short* __restrict__ hd,      // [N][64] bf16
        const short* __restrict__ pWr,    // [6][4][2][512]
        const short* __restrict__ pWlin,  // [4][4][512]
        const float* __restrict__ blin,
        const short* __restrict__ pW2,    // [4][2][512]
        const float* __restrict__ b2,
        float* __restrict__ out, int N) {
    __shared__ unsigned short sS[4][NRAT][16][68];   // 68 = 64 + 4 pad (2-way banks)
    const int lane = threadIdx.x & 63;
    const int w = threadIdx.x >> 6;
    const int n0 = (blockIdx.x * 4 + w) * 16;
    if (n0 >= N) return;

#define BFLD(mm) __uint_as_float(((unsigned)h_src[((size_t)((mm) & 0x1FFFFu)) * D + lane]) << 16)
#define ACC(mm, v) { unsigned rr = ((mm) >> 17) & 7u;                        \
        if (rr == 0) a0 += (v); else if (rr == 1) a1 += (v);                 \
        else if (rr == 2) a2 += (v); else if (rr == 3) a3 += (v);            \
        else if (rr == 4) a4 += (v); else a5 += (v); }

    // ---- Phase 1: gather 16 nodes
    for (int t = 0; t < 16; ++t) {
        int n = n0 + t; if (n > N - 1) n = N - 1;
        int b = off[n], e = off[n + 1];
        float a0 = 0.f, a1 = 0.f, a2 = 0.f, a3 = 0.f, a4 = 0.f, a5 = 0.f;
        for (int base = b; base < e; base += 64) {
            int idx = base + lane; if (idx > e - 1) idx = e - 1;
            unsigned meta = packed[idx];
            int cnt = e - base; if (cnt > 64) cnt = 64;
            int j = 0;
            for (; j + 4 <= cnt; j += 4) {
                unsigned m0 = (unsigned)__builtin_amdgcn_readlane((int)meta, j);
                unsigned m1 = (unsigned)__builtin_amdgcn_readlane((int)meta, j + 1);
                unsigned m2 = (unsigned)__builtin_amdgcn_readlane((int)meta, j + 2);
                unsigned m3 = (unsigned)__builtin_amdgcn_readlane((int)meta, j + 3);
                float v0 = BFLD(m0), v1 = BFLD(m1), v2 = BFLD(m2), v3 = BFLD(m3);
                ACC(m0, v0); ACC(m1, v1); ACC(m2, v2); ACC(m3, v3);
            }
            for (; j < cnt; ++j) {
                unsigned mm = (unsigned)__builtin_amdgcn_readlane((int)meta, j);
                float v = BFLD(mm);
                ACC(mm, v);
            }
        }
        sS[w][0][t][lane] = (unsigned short)f2bf(a0);
        sS[w][1][t][lane] = (unsigned short)f2bf(a1);
        sS[w][2][t][lane] = (unsigned short)f2bf(a2);
        sS[w][3][t][lane] = (unsigned short)f2bf(a3);
        sS[w][4][t][lane] = (unsigned short)f2bf(a4);
        sS[w][5][t][lane] = (unsigned short)f2bf(a5);
    }
#undef BFLD
#undef ACC

    // ---- Phase 2: MFMA transform (per wave, own LDS region; no barrier needed)
    const int m = lane & 15, q = lane >> 4;
    int nrow = n0 + m; if (nrow > N - 1) nrow = N - 1;

    bf16x8 bS[NRAT][2];
    #pragma unroll
    for (int r = 0; r < NRAT; ++r)
        #pragma unroll
        for (int kt = 0; kt < 2; ++kt) {
            const unsigned short* p = &sS[w][r][m][kt * 32 + q * 8];
            Frag8 f;
            f.h[0] = *(const s16x4*)p;
            f.h[1] = *(const s16x4*)(p + 4);
            bS[r][kt] = f.v;
        }
    bf16x8 bH[2];
    {
        const unsigned short* ph = hd + (size_t)nrow * D + q * 8;
        bH[0] = *(const bf16x8*)(ph);
        bH[1] = *(const bf16x8*)(ph + 32);
    }
    int deg = off[nrow + 1] - off[nrow];
    float inv = 1.0f / fmaxf((float)deg, 1.0f);

    // GEMM1: hn^T[i, n]
    f32x4 acc1[4] = {};
    #pragma unroll
    for (int it = 0; it < 4; ++it)
        #pragma unroll
        for (int r = 0; r < NRAT; ++r)
            #pragma unroll
            for (int kt = 0; kt < 2; ++kt) {
                bf16x8 a = *(const bf16x8*)(pWr + (((r * 4 + it) * 2 + kt) << 9) + (lane << 3));
                acc1[it] = __builtin_amdgcn_mfma_f32_16x16x32_bf16(a, bS[r][kt], acc1[it], 0, 0, 0);
            }
    #pragma unroll
    for (int it = 0; it < 4; ++it)
        #pragma unroll
        for (int rg = 0; rg < 4; ++rg) acc1[it][rg] *= inv;

    // C1 -> B2 frags
    const int srcA = ((q & 1) << 5) + m;
    const int srcB = srcA + 16;
    const bool hiq = (q >> 1) != 0;
    uint32_t u0[4], u1[4];
    #pragma unroll
    for (int it = 0; it < 4; ++it) {
        u0[it] = pk2(acc1[it][0], acc1[it][1]);
        u1[it] = pk2(acc1[it][2], acc1[it][3]);
    }
    bf16x8 bHN[2];
    #pragma unroll
    for (int ww = 0; ww < 2; ++ww) {
        uint32_t aa0 = (uint32_t)__shfl((int)u0[2*ww],   srcA), bb0 = (uint32_t)__shfl((int)u0[2*ww+1], srcA);
        uint32_t aa1 = (uint32_t)__shfl((int)u1[2*ww],   srcA), bb1 = (uint32_t)__shfl((int)u1[2*ww+1], srcA);
        uint32_t aa2 = (uint32_t)__shfl((int)u0[2*ww],   srcB), bb2 = (uint32_t)__shfl((int)u0[2*ww+1], srcB);
        uint32_t aa3 = (uint32_t)__shfl((int)u1[2*ww],   srcB), bb3 = (uint32_t)__shfl((int)u1[2*ww+1], srcB);
        FragU f;
        f.u[0] = hiq ? bb0 : aa0;
        f.u[1] = hiq ? bb1 : aa1;
        f.u[2] = hiq ? bb2 : aa2;
        f.u[3] = hiq ? bb3 : aa3;
        bHN[ww] = f.v;
    }

    // GEMM2: h2^T[o, n]
    f32x4 acc2[4] = {};
    #pragma unroll
    for (int it = 0; it < 4; ++it)
        #pragma unroll
        for (int kt = 0; kt < 4; ++kt) {
            bf16x8 a = *(const bf16x8*)(pWlin + (((it * 4) + kt) << 9) + (lane << 3));
            bf16x8 b = (kt < 2) ? bH[kt] : bHN[kt - 2];
            acc2[it] = __builtin_amdgcn_mfma_f32_16x16x32_bf16(a, b, acc2[it], 0, 0, 0);
        }

    // bias + relu -> A3 frags
    float vbl = blin[lane];
    #pragma unroll
    for (int it = 0; it < 4; ++it) {
        float h0 = fmaxf(acc2[it][0] + __shfl(vbl, it * 16 + q * 4 + 0), 0.f);
        float h1 = fmaxf(acc2[it][1] + __shfl(vbl, it * 16 + q * 4 + 1), 0.f);
        float h2 = fmaxf(acc2[it][2] + __shfl(vbl, it * 16 + q * 4 + 2), 0.f);
        float h3 = fmaxf(acc2[it][3] + __shfl(vbl, it * 16 + q * 4 + 3), 0.f);
        u0[it] = pk2(h0, h1);
        u1[it] = pk2(h2, h3);
    }
    bf16x8 bA3[2];
    #pragma unroll
    for (int ww = 0; ww < 2; ++ww) {
        uint32_t aa0 = (uint32_t)__shfl((int)u0[2*ww],   srcA), bb0 = (uint32_t)__shfl((int)u0[2*ww+1], srcA);
        uint32_t aa1 = (uint32_t)__shfl((int)u1[2*ww],   srcA), bb1 = (uint32_t)__shfl((int)u1[2*ww+1], srcA);
        uint32_t aa2 = (uint32_t)__shfl((int)u0[2*ww],   srcB), bb2 = (uint32_t)__shfl((int)u0[2*ww+1], srcB);
        uint32_t aa3 = (uint32_t)__shfl((int)u1[2*ww],   srcB), bb3 = (uint32_t)__shfl((int)u1[2*ww+1], srcB);
        FragU f;
        f.u[0] = hiq ? bb0 : aa0;
        f.u[1] = hiq ? bb1 : aa1;
        f.u[2] = hiq ? bb2 : aa2;
        f.u[3] = hiq ? bb3 : aa3;
        bA3[ww] = f.v;
    }

    // GEMM3: out
    f32x4 acc3[4] = {};
    #pragma unroll
    for (int ct = 0; ct < 4; ++ct)
        #pragma unroll
        for (int kt = 0; kt < 2; ++kt) {
            bf16x8 b = *(const bf16x8*)(pW2 + (((ct * 2) + kt) << 9) + (lane << 3));
            acc3[ct] = __builtin_amdgcn_mfma_f32_16x16x32_bf16(bA3[kt], b, acc3[ct], 0, 0, 0);
        }
    #pragma unroll
    for (int ct = 0; ct < 4; ++ct) {
        float bb = b2[ct * 16 + m];
        #pragma unroll
        for (int rg = 0; rg < 4; ++rg) {
            int n = n0 + q * 4 + rg;
            if (n < N) out[(size_t)n * D + ct * 16 + m] = acc3[ct][rg] + bb;
        }
    }
}

extern "C" void kernel_launch(void* const* d_in, const int* in_sizes, int n_in,
                              void* d_out, int out_size, void* d_ws, size_t ws_size,
                              hipStream_t stream) {
    const int*   user_ids   = (const int*)  d_in[0];
    const int*   item_ids   = (const int*)  d_in[1];
    const int*   gender     = (const int*)  d_in[2];
    const int*   genres     = (const int*)  d_in[3];
    const int*   edge_user  = (const int*)  d_in[4];
    const int*   edge_item  = (const int*)  d_in[5];
    const int*   rating     = (const int*)  d_in[6];
    const float* user_emb   = (const float*)d_in[7];
    const float* item_emb   = (const float*)d_in[8];
    const float* gender_emb = (const float*)d_in[9];
    const float* genre_emb  = (const float*)d_in[10];
    const float* Wr_watched   = (const float*)d_in[11];
    const float* Wr_watchedby = (const float*)d_in[12];
    const float* Ww  = (const float*)d_in[13];
    const float* bw  = (const float*)d_in[14];
    const float* Wwb = (const float*)d_in[15];
    const float* bwb = (const float*)d_in[16];
    const float* Wf  = (const float*)d_in[17];
    const float* bf  = (const float*)d_in[18];
    const float* Vf  = (const float*)d_in[19];
    const float* bv  = (const float*)d_in[20];

    const int NU = in_sizes[0];
    const int NI = in_sizes[1];
    const int E  = in_sizes[4];
    const int SH_I = 8, SH_U = 9;
    const int NBI = (NI + (1 << SH_I) - 1) >> SH_I;   // <=256
    const int NBU = (NU + (1 << SH_U) - 1) >> SH_U;   // <=256

    float* out_f    = (float*)d_out;
    float* user_out = out_f;                       // [NU,64]
    float* item_out = out_f + (size_t)NU * D;      // [NI,64]

    // ws layout: hu,hi (bf16), bf16 weight packs, int metadata, staged records
    unsigned short* hu = (unsigned short*)d_ws;
    unsigned short* hi = hu + (size_t)NU * D;
    size_t byteOff = (((size_t)(NU + NI) * D * 2) + 15) & ~(size_t)15;
    short* pWrW  = (short*)((char*)d_ws + byteOff);
    short* pWrWB = pWrW  + 24576;
    short* pWw   = pWrWB + 24576;
    short* pWwb  = pWw   + 8192;
    short* pVf   = pWwb  + 8192;
    short* pWf   = pVf   + 4096;
    int* coarseCntI = (int*)(pWf + 4096);   // 256
    int* coarseCntU = coarseCntI + 256;     // 256 (memset together)
    int* coarseOffI = coarseCntU + 256;     // 257
    int* coarseOffU = coarseOffI + 257;     // 257
    int* coarseCurI = coarseOffU + 257;     // 256
    int* coarseCurU = coarseCurI + 256;     // 256
    int* offI   = coarseCurU + 256;         // NI+1
    int* offU   = offI + NI + 1;            // NU+1
    unsigned* staged = (unsigned*)(offU + NU + 1);  // E (reused by both dirs)

    // 1. node features + weight packing + coarse binning metadata
    int totalh = (NU + NI) * 16;
    build_h<<<(totalh + 255) / 256, 256, 0, stream>>>(
        user_ids, item_ids, gender, genres,
        user_emb, item_emb, gender_emb, genre_emb, hu, hi, NU, NI);
    prep_weights<<<288, 256, 0, stream>>>(Wr_watched, Wr_watchedby, Ww, Wwb, Vf, Wf,
                                          pWrW, pWrWB, pWw, pWwb, pVf, pWf);
    hipMemsetAsync(coarseCntI, 0, 512 * sizeof(int), stream);
    coarse_hist<<<512, 256, 0, stream>>>(edge_item, coarseCntI, E, SH_I);
    coarse_hist<<<512, 256, 0, stream>>>(edge_user, coarseCntU, E, SH_U);
    coarse_scan<<<1, 256, 0, stream>>>(coarseCntI, coarseOffI, coarseCurI, NBI, E);
    coarse_scan<<<1, 256, 0, stream>>>(coarseCntU, coarseOffU, coarseCurU, NBU, E);

    const int nTilesA = (E + 2047) / 2048;

    // 2. direction 'watched' (users -> items), dst = items
    multisplit_A<<<nTilesA, 256, 0, stream>>>(edge_item, edge_user, rating,
                                              coarseCurI, staged, E, SH_I);
    multisplit_B<<<NBI, 256, 0, stream>>>(staged, coarseOffI, offI, NI, E, SH_I);
    fused_gt<<<(NI + 63) / 64, 256, 0, stream>>>(offI, staged, hu, hi,
                                                 pWrW, pWw, bw, pVf, bv, item_out, NI);

    // 3. direction 'watchedby' (items -> users), dst = users
    multisplit_A<<<nTilesA, 256, 0, stream>>>(edge_user, edge_item, rating,
                                              coarseCurU, staged, E, SH_U);
    multisplit_B<<<NBU, 256, 0, stream>>>(staged, coarseOffU, offU, NU, E, SH_U);
    fused_gt<<<(NU + 63) / 64, 256, 0, stream>>>(offU, staged, hi, hu,
                                                 pWrWB, pWwb, bwb, pWf, bf, user_out, NU);
}

// Round 7
// 330.376 us; speedup vs baseline: 1.6997x; 1.6997x over previous
//
#include <hip/hip_runtime.h>
#include <hip/hip_bf16.h>

#define D 64
#define NRAT 6

typedef float f32x4 __attribute__((ext_vector_type(4)));
typedef short bf16x8 __attribute__((ext_vector_type(8)));

union FragU { uint32_t u[4]; bf16x8 v; };

__device__ __forceinline__ short f2bf(float f) {
    __hip_bfloat16 h = __float2bfloat16(f);
    union { __hip_bfloat16 h; short s; } c; c.h = h; return c.s;
}
__device__ __forceinline__ uint32_t pk2(float a, float b) {
    union { short s[2]; uint32_t u; } c; c.s[0] = f2bf(a); c.s[1] = f2bf(b); return c.u;
}

// hu[n] = bf16(user_emb[user_ids[n]] + gender_emb[gender[n]]);  hi analog.
__global__ void build_h(const int* __restrict__ uid, const int* __restrict__ iid,
                        const int* __restrict__ gender, const int* __restrict__ genres,
                        const float* __restrict__ user_emb, const float* __restrict__ item_emb,
                        const float* __restrict__ gender_emb, const float* __restrict__ genre_emb,
                        unsigned short* __restrict__ hu, unsigned short* __restrict__ hi,
                        int NU, int NI) {
    int t = blockIdx.x * blockDim.x + threadIdx.x;
    int total = (NU + NI) * 16;            // one float4 (4 dims) per thread
    if (t >= total) return;
    int row = t >> 4, c = t & 15;
    uint2 o;
    if (row < NU) {
        int u = uid[row], g = gender[row];
        float4 a = ((const float4*)user_emb)[(size_t)u * 16 + c];
        float4 b = ((const float4*)gender_emb)[(size_t)g * 16 + c];
        o.x = pk2(a.x + b.x, a.y + b.y); o.y = pk2(a.z + b.z, a.w + b.w);
        ((uint2*)hu)[(size_t)row * 16 + c] = o;
    } else {
        int r2 = row - NU;
        int it = iid[r2], ge = genres[r2];
        float4 a = ((const float4*)item_emb)[(size_t)it * 16 + c];
        float4 b = ((const float4*)genre_emb)[(size_t)ge * 16 + c];
        o.x = pk2(a.x + b.x, a.y + b.y); o.y = pk2(a.z + b.z, a.w + b.w);
        ((uint2*)hi)[(size_t)r2 * 16 + c] = o;
    }
}

// Coarse histogram over dst>>shift (<=256 buckets), LDS-aggregated.
__global__ __launch_bounds__(256) void coarse_hist(const int* __restrict__ dst,
                                                   int* __restrict__ cnt, int E, int shift) {
    __shared__ int h[256];
    h[threadIdx.x] = 0; __syncthreads();
    for (int i = blockIdx.x * blockDim.x + threadIdx.x; i < E; i += gridDim.x * blockDim.x)
        atomicAdd(&h[dst[i] >> shift], 1);
    __syncthreads();
    int v = h[threadIdx.x];
    if (v) atomicAdd(&cnt[threadIdx.x], v);
}

// 1-block exclusive scan of <=256 coarse counts -> coarseOff (+total) and cursor copy.
__global__ __launch_bounds__(256) void coarse_scan(const int* __restrict__ cnt,
                                                   int* __restrict__ coarseOff,
                                                   int* __restrict__ coarseCur, int NB, int E) {
    __shared__ int p[256];
    int tid = threadIdx.x;
    int v = (tid < NB) ? cnt[tid] : 0;
    p[tid] = v; __syncthreads();
    for (int dd = 1; dd < 256; dd <<= 1) {
        int a = (tid >= dd) ? p[tid - dd] : 0;
        __syncthreads();
        p[tid] += a;
        __syncthreads();
    }
    int excl = p[tid] - v;
    if (tid < NB) { coarseOff[tid] = excl; coarseCur[tid] = excl; }
    if (tid == 0) coarseOff[NB] = E;
}

// Pass A: coarse-bucket edges. Record = src(17b) | r(3b) | dstLow(<=9b at bit 20).
__global__ __launch_bounds__(256) void multisplit_A(
        const int* __restrict__ dst, const int* __restrict__ src,
        const int* __restrict__ rating, int* __restrict__ coarseCur,
        unsigned* __restrict__ staged, int E, int shift) {
    __shared__ unsigned srt[2048];
    __shared__ int sft[2048];
    __shared__ int hist[256], pfx[256], shm[256];
    const int tid = threadIdx.x;
    const int tile = blockIdx.x * 2048;
    int cnt = E - tile; if (cnt > 2048) cnt = 2048;
    hist[tid] = 0;
    __syncthreads();
    unsigned rec[8]; int bk[8];
    #pragma unroll
    for (int k = 0; k < 8; ++k) {
        int i = tile + k * 256 + tid;
        bk[k] = -1;
        if (i < E) {
            int d = dst[i], s = src[i], r = rating[i];
            bk[k] = d >> shift;
            rec[k] = (unsigned)s | ((unsigned)r << 17) | ((unsigned)(d & ((1 << shift) - 1)) << 20);
            atomicAdd(&hist[bk[k]], 1);
        }
    }
    __syncthreads();
    pfx[tid] = hist[tid];
    __syncthreads();
    for (int dd = 1; dd < 256; dd <<= 1) {
        int a = (tid >= dd) ? pfx[tid - dd] : 0;
        __syncthreads();
        pfx[tid] += a;
        __syncthreads();
    }
    int h = hist[tid];
    int excl = pfx[tid] - h;
    int gb = 0;
    if (h > 0) gb = atomicAdd(&coarseCur[tid], h);
    shm[tid] = gb - excl;
    __syncthreads();
    hist[tid] = excl;          // reuse as local cursor
    __syncthreads();
    #pragma unroll
    for (int k = 0; k < 8; ++k) {
        if (bk[k] >= 0) {
            int p = atomicAdd(&hist[bk[k]], 1);
            srt[p] = rec[k];
            sft[p] = shm[bk[k]];
        }
    }
    __syncthreads();
    for (int i = tid; i < cnt; i += 256)
        staged[sft[i] + i] = srt[i];
}

// Pass B: one block per coarse bucket. LDS-stage records, local 512-slot hist
// + scan -> CSR off[] for this dst range, then in-place sorted write.
__global__ __launch_bounds__(256) void multisplit_B(
        unsigned* __restrict__ staged, const int* __restrict__ coarseOff,
        int* __restrict__ off, int N, int E, int shift) {
    __shared__ unsigned rec[16384];
    __shared__ int hist[512], pfx[512];
    const int tid = threadIdx.x;
    const int b = blockIdx.x;
    const int range = 1 << shift;
    int cbase = coarseOff[b];
    int cnt = coarseOff[b + 1] - cbase;
    if (cnt > 16384) cnt = 16384;   // safety guard (never expected)
    hist[tid] = 0; hist[tid + 256] = 0;
    __syncthreads();
    for (int i = tid; i < cnt; i += 256) {
        unsigned x = staged[cbase + i];
        rec[i] = x;
        atomicAdd(&hist[x >> 20], 1);
    }
    __syncthreads();
    pfx[tid] = hist[tid]; pfx[tid + 256] = hist[tid + 256];
    __syncthreads();
    for (int dd = 1; dd < 256; dd <<= 1) {
        int a = (tid >= dd) ? pfx[tid - dd] : 0;
        int c = (tid >= dd) ? pfx[tid + 256 - dd] : 0;
        __syncthreads();
        pfx[tid] += a; pfx[tid + 256] += c;
        __syncthreads();
    }
    int tot0 = pfx[255];
    __syncthreads();
    pfx[tid + 256] += tot0;
    __syncthreads();
    int e0 = pfx[tid] - hist[tid];
    int e1 = pfx[tid + 256] - hist[tid + 256];
    __syncthreads();
    hist[tid] = e0; hist[tid + 256] = e1;   // cursors
    int dbase = b << shift;
    if (dbase + tid < N) off[dbase + tid] = cbase + e0;
    if (range > 256 && dbase + tid + 256 < N) off[dbase + tid + 256] = cbase + e1;
    if (b == gridDim.x - 1 && tid == 0) off[N] = E;
    __syncthreads();
    for (int i = tid; i < cnt; i += 256) {
        unsigned x = rec[i];
        int p = atomicAdd(&hist[x >> 20], 1);
        staged[cbase + p] = x;
    }
}

// One wave per dst node (lane = dim): batch-load 64 edge metas coalesced,
// broadcast via readlane (uniform rating -> scalar branch), gather 128B bf16
// rows, accumulate per-rating f32 sums, store mean-scaled bf16 S rows once.
__global__ __launch_bounds__(256) void gather_reduce(
        const int* __restrict__ off, const unsigned* __restrict__ packed,
        const unsigned short* __restrict__ h_src, unsigned short* __restrict__ S, int Ndst) {
    int lane = threadIdx.x & 63;
    int n = (blockIdx.x * blockDim.x + threadIdx.x) >> 6;
    if (n >= Ndst) return;
    int b = off[n], e = off[n + 1];
    float a0 = 0.f, a1 = 0.f, a2 = 0.f, a3 = 0.f, a4 = 0.f, a5 = 0.f;

#define BFLD(mm) __uint_as_float(((unsigned)h_src[((size_t)((mm) & 0x1FFFFu)) * D + lane]) << 16)
#define ACC(mm, v) { unsigned rr = ((mm) >> 17) & 7u;                        \
        if (rr == 0) a0 += (v); else if (rr == 1) a1 += (v);                 \
        else if (rr == 2) a2 += (v); else if (rr == 3) a3 += (v);            \
        else if (rr == 4) a4 += (v); else a5 += (v); }

    for (int base = b; base < e; base += 64) {
        int idx = base + lane; if (idx > e - 1) idx = e - 1;
        unsigned meta = packed[idx];
        int cnt = e - base; if (cnt > 64) cnt = 64;
        int j = 0;
        for (; j + 4 <= cnt; j += 4) {
            unsigned m0 = (unsigned)__builtin_amdgcn_readlane((int)meta, j);
            unsigned m1 = (unsigned)__builtin_amdgcn_readlane((int)meta, j + 1);
            unsigned m2 = (unsigned)__builtin_amdgcn_readlane((int)meta, j + 2);
            unsigned m3 = (unsigned)__builtin_amdgcn_readlane((int)meta, j + 3);
            float v0 = BFLD(m0), v1 = BFLD(m1), v2 = BFLD(m2), v3 = BFLD(m3);
            ACC(m0, v0); ACC(m1, v1); ACC(m2, v2); ACC(m3, v3);
        }
        for (; j < cnt; ++j) {
            unsigned mm = (unsigned)__builtin_amdgcn_readlane((int)meta, j);
            float v = BFLD(mm);
            ACC(mm, v);
        }
    }
#undef BFLD
#undef ACC

    float inv = 1.0f / fmaxf((float)(e - b), 1.0f);   // fold mean into S
    size_t s0 = (size_t)n * D + lane;
    size_t st = (size_t)Ndst * D;
    S[s0]          = (unsigned short)f2bf(a0 * inv);
    S[s0 +     st] = (unsigned short)f2bf(a1 * inv);
    S[s0 + 2 * st] = (unsigned short)f2bf(a2 * inv);
    S[s0 + 3 * st] = (unsigned short)f2bf(a3 * inv);
    S[s0 + 4 * st] = (unsigned short)f2bf(a4 * inv);
    S[s0 + 5 * st] = (unsigned short)f2bf(a5 * inv);
}

// One-time: pack weights (bf16) into MFMA fragment order.
__global__ void prep_weights(const float* __restrict__ Wr_w, const float* __restrict__ Wr_wb,
                             const float* __restrict__ Ww, const float* __restrict__ Wwb,
                             const float* __restrict__ Vf, const float* __restrict__ Wf,
                             short* __restrict__ pWrW, short* __restrict__ pWrWB,
                             short* __restrict__ pWw, short* __restrict__ pWwb,
                             short* __restrict__ pVf, short* __restrict__ pWf) {
    int t = blockIdx.x * blockDim.x + threadIdx.x;
    const float* src; short* dst; int K; int idx;
    if      (t < 24576) { src = Wr_w;  dst = pWrW;  K = 64;  idx = t; }
    else if (t < 49152) { src = Wr_wb; dst = pWrWB; K = 64;  idx = t - 24576; }
    else if (t < 57344) { src = Ww;    dst = pWw;   K = 128; idx = t - 49152; }
    else if (t < 65536) { src = Wwb;   dst = pWwb;  K = 128; idx = t - 57344; }
    else if (t < 69632) { src = Vf;    dst = pVf;   K = 64;  idx = t - 65536; }
    else if (t < 73728) { src = Wf;    dst = pWf;   K = 64;  idx = t - 69632; }
    else return;
    int per  = 64 * K;
    int sub  = idx / per;            // r for Wr packs, 0 otherwise
    int li   = idx % per;
    int e    = li & 7;
    int lane = (li >> 3) & 63;
    int frag = li >> 9;              // t16*(K/32) + tk
    int nkt  = K >> 5;
    int t16  = frag / nkt, tk = frag % nkt;
    int row  = t16 * 16 + (lane & 15);
    int col  = tk * 32 + (lane >> 4) * 8 + e;
    dst[idx] = f2bf(src[((size_t)(sub * 64 + row)) * K + col]);
}

// Fused per-16-node-tile MFMA transform (one wave per tile), all-bf16 inputs:
//   GEMM1 (transposed): hn^T = sum_r Wr[r] @ Smean[r,tile]^T   (mean pre-folded)
//   GEMM2 (transposed): h2^T = relu(Wlin @ [hd|hn]^T + blin)
//   GEMM3 (normal):     out  = h2 @ W2^T + b2
__global__ __launch_bounds__(256) void transform_mfma(
        const unsigned short* __restrict__ S,   // [6][N][64] bf16, mean-scaled
        const unsigned short* __restrict__ hd,  // [N][64] bf16
        const short* __restrict__ pWr,    // [6][4][2][512]
        const short* __restrict__ pWlin,  // [4][4][512]
        const float* __restrict__ blin,
        const short* __restrict__ pW2,    // [4][2][512]
        const float* __restrict__ b2,
        float* __restrict__ out, int N) {
    const int lane = threadIdx.x & 63;
    const int m = lane & 15, q = lane >> 4;
    const int wave = (blockIdx.x * blockDim.x + threadIdx.x) >> 6;
    const int n0 = wave * 16;
    if (n0 >= N) return;
    int nrow = n0 + m; if (nrow > N - 1) nrow = N - 1;

    // ---- B1 frags straight from bf16 S: lane holds S[r][n0+m][kt*32+q*8+e]
    bf16x8 bS[NRAT][2];
    #pragma unroll
    for (int r = 0; r < NRAT; ++r) {
        const unsigned short* p = S + ((size_t)r * N + nrow) * D + q * 8;
        bS[r][0] = *(const bf16x8*)(p);
        bS[r][1] = *(const bf16x8*)(p + 32);
    }
    bf16x8 bH[2];
    {
        const unsigned short* ph = hd + (size_t)nrow * D + q * 8;
        bH[0] = *(const bf16x8*)(ph);
        bH[1] = *(const bf16x8*)(ph + 32);
    }

    // ---- GEMM1: hn^T[i, n],  C1: col=m=node, row=it*16+q*4+reg = i
    f32x4 acc1[4] = {};
    #pragma unroll
    for (int it = 0; it < 4; ++it)
        #pragma unroll
        for (int r = 0; r < NRAT; ++r)
            #pragma unroll
            for (int kt = 0; kt < 2; ++kt) {
                bf16x8 a = *(const bf16x8*)(pWr + (((r * 4 + it) * 2 + kt) << 9) + (lane << 3));
                acc1[it] = __builtin_amdgcn_mfma_f32_16x16x32_bf16(a, bS[r][kt], acc1[it], 0, 0, 0);
            }

    // ---- C1 -> B2 frags (hn part of cat): lane needs hn[n0+m][32w+8q+e]
    const int srcA = ((q & 1) << 5) + m;
    const int srcB = srcA + 16;
    const bool hiq = (q >> 1) != 0;
    uint32_t u0[4], u1[4];
    #pragma unroll
    for (int it = 0; it < 4; ++it) {
        u0[it] = pk2(acc1[it][0], acc1[it][1]);
        u1[it] = pk2(acc1[it][2], acc1[it][3]);
    }
    bf16x8 bHN[2];
    #pragma unroll
    for (int w = 0; w < 2; ++w) {
        uint32_t aa0 = (uint32_t)__shfl((int)u0[2*w],   srcA), bb0 = (uint32_t)__shfl((int)u0[2*w+1], srcA);
        uint32_t aa1 = (uint32_t)__shfl((int)u1[2*w],   srcA), bb1 = (uint32_t)__shfl((int)u1[2*w+1], srcA);
        uint32_t aa2 = (uint32_t)__shfl((int)u0[2*w],   srcB), bb2 = (uint32_t)__shfl((int)u0[2*w+1], srcB);
        uint32_t aa3 = (uint32_t)__shfl((int)u1[2*w],   srcB), bb3 = (uint32_t)__shfl((int)u1[2*w+1], srcB);
        FragU f;
        f.u[0] = hiq ? bb0 : aa0;
        f.u[1] = hiq ? bb1 : aa1;
        f.u[2] = hiq ? bb2 : aa2;
        f.u[3] = hiq ? bb3 : aa3;
        bHN[w] = f.v;
    }

    // ---- GEMM2: h2^T[o, n]
    f32x4 acc2[4] = {};
    #pragma unroll
    for (int it = 0; it < 4; ++it)
        #pragma unroll
        for (int kt = 0; kt < 4; ++kt) {
            bf16x8 a = *(const bf16x8*)(pWlin + (((it * 4) + kt) << 9) + (lane << 3));
            bf16x8 b = (kt < 2) ? bH[kt] : bHN[kt - 2];
            acc2[it] = __builtin_amdgcn_mfma_f32_16x16x32_bf16(a, b, acc2[it], 0, 0, 0);
        }

    // ---- bias + relu -> A3 frags
    float vbl = blin[lane];
    #pragma unroll
    for (int it = 0; it < 4; ++it) {
        float h0 = fmaxf(acc2[it][0] + __shfl(vbl, it * 16 + q * 4 + 0), 0.f);
        float h1 = fmaxf(acc2[it][1] + __shfl(vbl, it * 16 + q * 4 + 1), 0.f);
        float h2 = fmaxf(acc2[it][2] + __shfl(vbl, it * 16 + q * 4 + 2), 0.f);
        float h3 = fmaxf(acc2[it][3] + __shfl(vbl, it * 16 + q * 4 + 3), 0.f);
        u0[it] = pk2(h0, h1);
        u1[it] = pk2(h2, h3);
    }
    bf16x8 bA3[2];
    #pragma unroll
    for (int w = 0; w < 2; ++w) {
        uint32_t aa0 = (uint32_t)__shfl((int)u0[2*w],   srcA), bb0 = (uint32_t)__shfl((int)u0[2*w+1], srcA);
        uint32_t aa1 = (uint32_t)__shfl((int)u1[2*w],   srcA), bb1 = (uint32_t)__shfl((int)u1[2*w+1], srcA);
        uint32_t aa2 = (uint32_t)__shfl((int)u0[2*w],   srcB), bb2 = (uint32_t)__shfl((int)u0[2*w+1], srcB);
        uint32_t aa3 = (uint32_t)__shfl((int)u1[2*w],   srcB), bb3 = (uint32_t)__shfl((int)u1[2*w+1], srcB);
        FragU f;
        f.u[0] = hiq ? bb0 : aa0;
        f.u[1] = hiq ? bb1 : aa1;
        f.u[2] = hiq ? bb2 : aa2;
        f.u[3] = hiq ? bb3 : aa3;
        bA3[w] = f.v;
    }

    // ---- GEMM3 (normal): C3[node_row, o],  row=q*4+reg=node, col=ct*16+m=o
    f32x4 acc3[4] = {};
    #pragma unroll
    for (int ct = 0; ct < 4; ++ct)
        #pragma unroll
        for (int kt = 0; kt < 2; ++kt) {
            bf16x8 b = *(const bf16x8*)(pW2 + (((ct * 2) + kt) << 9) + (lane << 3));
            acc3[ct] = __builtin_amdgcn_mfma_f32_16x16x32_bf16(bA3[kt], b, acc3[ct], 0, 0, 0);
        }
    #pragma unroll
    for (int ct = 0; ct < 4; ++ct) {
        float bb = b2[ct * 16 + m];
        #pragma unroll
        for (int rg = 0; rg < 4; ++rg) {
            int n = n0 + q * 4 + rg;
            if (n < N) out[(size_t)n * D + ct * 16 + m] = acc3[ct][rg] + bb;
        }
    }
}

extern "C" void kernel_launch(void* const* d_in, const int* in_sizes, int n_in,
                              void* d_out, int out_size, void* d_ws, size_t ws_size,
                              hipStream_t stream) {
    const int*   user_ids   = (const int*)  d_in[0];
    const int*   item_ids   = (const int*)  d_in[1];
    const int*   gender     = (const int*)  d_in[2];
    const int*   genres     = (const int*)  d_in[3];
    const int*   edge_user  = (const int*)  d_in[4];
    const int*   edge_item  = (const int*)  d_in[5];
    const int*   rating     = (const int*)  d_in[6];
    const float* user_emb   = (const float*)d_in[7];
    const float* item_emb   = (const float*)d_in[8];
    const float* gender_emb = (const float*)d_in[9];
    const float* genre_emb  = (const float*)d_in[10];
    const float* Wr_watched   = (const float*)d_in[11];
    const float* Wr_watchedby = (const float*)d_in[12];
    const float* Ww  = (const float*)d_in[13];
    const float* bw  = (const float*)d_in[14];
    const float* Wwb = (const float*)d_in[15];
    const float* bwb = (const float*)d_in[16];
    const float* Wf  = (const float*)d_in[17];
    const float* bf  = (const float*)d_in[18];
    const float* Vf  = (const float*)d_in[19];
    const float* bv  = (const float*)d_in[20];

    const int NU = in_sizes[0];
    const int NI = in_sizes[1];
    const int E  = in_sizes[4];
    const int maxN = (NU > NI) ? NU : NI;
    const int SH_I = 8, SH_U = 9;
    const int NBI = (NI + (1 << SH_I) - 1) >> SH_I;   // <=256
    const int NBU = (NU + (1 << SH_U) - 1) >> SH_U;   // <=256

    float* out_f    = (float*)d_out;
    float* user_out = out_f;                       // [NU,64]
    float* item_out = out_f + (size_t)NU * D;      // [NI,64]

    // ws layout (bf16 first): hu, hi, S[6*maxN*64], weight packs, ints, staged
    unsigned short* hu = (unsigned short*)d_ws;
    unsigned short* hi = hu + (size_t)NU * D;
    unsigned short* S  = hi + (size_t)NI * D;
    size_t byteOff = (((size_t)(NU + NI) * D + (size_t)NRAT * maxN * D) * 2 + 15) & ~(size_t)15;
    short* pWrW  = (short*)((char*)d_ws + byteOff);
    short* pWrWB = pWrW  + 24576;
    short* pWw   = pWrWB + 24576;
    short* pWwb  = pWw   + 8192;
    short* pVf   = pWwb  + 8192;
    short* pWf   = pVf   + 4096;
    int* coarseCntI = (int*)(pWf + 4096);   // 256
    int* coarseCntU = coarseCntI + 256;     // 256 (memset together)
    int* coarseOffI = coarseCntU + 256;     // 257
    int* coarseOffU = coarseOffI + 257;     // 257
    int* coarseCurI = coarseOffU + 257;     // 256
    int* coarseCurU = coarseCurI + 256;     // 256
    int* offI   = coarseCurU + 256;         // NI+1
    int* offU   = offI + NI + 1;            // NU+1
    unsigned* staged = (unsigned*)(offU + NU + 1);  // E (reused by both dirs)

    // 1. node features + weight packing + coarse binning metadata
    int totalh = (NU + NI) * 16;
    build_h<<<(totalh + 255) / 256, 256, 0, stream>>>(
        user_ids, item_ids, gender, genres,
        user_emb, item_emb, gender_emb, genre_emb, hu, hi, NU, NI);
    prep_weights<<<288, 256, 0, stream>>>(Wr_watched, Wr_watchedby, Ww, Wwb, Vf, Wf,
                                          pWrW, pWrWB, pWw, pWwb, pVf, pWf);
    hipMemsetAsync(coarseCntI, 0, 512 * sizeof(int), stream);
    coarse_hist<<<512, 256, 0, stream>>>(edge_item, coarseCntI, E, SH_I);
    coarse_hist<<<512, 256, 0, stream>>>(edge_user, coarseCntU, E, SH_U);
    coarse_scan<<<1, 256, 0, stream>>>(coarseCntI, coarseOffI, coarseCurI, NBI, E);
    coarse_scan<<<1, 256, 0, stream>>>(coarseCntU, coarseOffU, coarseCurU, NBU, E);

    const int nTilesA = (E + 2047) / 2048;

    // 2. direction 'watched' (users -> items), dst = items
    multisplit_A<<<nTilesA, 256, 0, stream>>>(edge_item, edge_user, rating,
                                              coarseCurI, staged, E, SH_I);
    multisplit_B<<<NBI, 256, 0, stream>>>(staged, coarseOffI, offI, NI, E, SH_I);
    gather_reduce<<<(NI + 3) / 4, 256, 0, stream>>>(offI, staged, hu, S, NI);
    {
        int tiles = (NI + 15) / 16, blocks = (tiles + 3) / 4;
        transform_mfma<<<blocks, 256, 0, stream>>>(S, hi, pWrW, pWw, bw, pVf, bv,
                                                   item_out, NI);
    }

    // 3. direction 'watchedby' (items -> users), dst = users
    multisplit_A<<<nTilesA, 256, 0, stream>>>(edge_user, edge_item, rating,
                                              coarseCurU, staged, E, SH_U);
    multisplit_B<<<NBU, 256, 0, stream>>>(staged, coarseOffU, offU, NU, E, SH_U);
    gather_reduce<<<(NU + 3) / 4, 256, 0, stream>>>(offU, staged, hi, S, NU);
    {
        int tiles = (NU + 15) / 16, blocks = (tiles + 3) / 4;
        transform_mfma<<<blocks, 256, 0, stream>>>(S, hu, pWrWB, pWwb, bwb, pWf, bf,
                                                   user_out, NU);
    }
}

// Round 8
// 300.779 us; speedup vs baseline: 1.8669x; 1.0984x over previous
//
#include <hip/hip_runtime.h>
#include <hip/hip_bf16.h>

#define D 64
#define NRAT 6

typedef float f32x4 __attribute__((ext_vector_type(4)));
typedef short bf16x8 __attribute__((ext_vector_type(8)));

union FragU { uint32_t u[4]; bf16x8 v; };

__device__ __forceinline__ short f2bf(float f) {
    __hip_bfloat16 h = __float2bfloat16(f);
    union { __hip_bfloat16 h; short s; } c; c.h = h; return c.s;
}
__device__ __forceinline__ uint32_t pk2(float a, float b) {
    union { short s[2]; uint32_t u; } c; c.s[0] = f2bf(a); c.s[1] = f2bf(b); return c.u;
}

// hu[n] = bf16(user_emb[user_ids[n]] + gender_emb[gender[n]]);  hi analog.
__global__ void build_h(const int* __restrict__ uid, const int* __restrict__ iid,
                        const int* __restrict__ gender, const int* __restrict__ genres,
                        const float* __restrict__ user_emb, const float* __restrict__ item_emb,
                        const float* __restrict__ gender_emb, const float* __restrict__ genre_emb,
                        unsigned short* __restrict__ hu, unsigned short* __restrict__ hi,
                        int NU, int NI) {
    int t = blockIdx.x * blockDim.x + threadIdx.x;
    int total = (NU + NI) * 16;            // one float4 (4 dims) per thread
    if (t >= total) return;
    int row = t >> 4, c = t & 15;
    uint2 o;
    if (row < NU) {
        int u = uid[row], g = gender[row];
        float4 a = ((const float4*)user_emb)[(size_t)u * 16 + c];
        float4 b = ((const float4*)gender_emb)[(size_t)g * 16 + c];
        o.x = pk2(a.x + b.x, a.y + b.y); o.y = pk2(a.z + b.z, a.w + b.w);
        ((uint2*)hu)[(size_t)row * 16 + c] = o;
    } else {
        int r2 = row - NU;
        int it = iid[r2], ge = genres[r2];
        float4 a = ((const float4*)item_emb)[(size_t)it * 16 + c];
        float4 b = ((const float4*)genre_emb)[(size_t)ge * 16 + c];
        o.x = pk2(a.x + b.x, a.y + b.y); o.y = pk2(a.z + b.z, a.w + b.w);
        ((uint2*)hi)[(size_t)r2 * 16 + c] = o;
    }
}

// Coarse histogram over dst>>shift (<=256 buckets), LDS-aggregated.
__global__ __launch_bounds__(256) void coarse_hist(const int* __restrict__ dst,
                                                   int* __restrict__ cnt, int E, int shift) {
    __shared__ int h[256];
    h[threadIdx.x] = 0; __syncthreads();
    for (int i = blockIdx.x * blockDim.x + threadIdx.x; i < E; i += gridDim.x * blockDim.x)
        atomicAdd(&h[dst[i] >> shift], 1);
    __syncthreads();
    int v = h[threadIdx.x];
    if (v) atomicAdd(&cnt[threadIdx.x], v);
}

// 1-block exclusive scan of <=256 coarse counts -> coarseOff (+total) and cursor copy.
__global__ __launch_bounds__(256) void coarse_scan(const int* __restrict__ cnt,
                                                   int* __restrict__ coarseOff,
                                                   int* __restrict__ coarseCur, int NB, int E) {
    __shared__ int p[256];
    int tid = threadIdx.x;
    int v = (tid < NB) ? cnt[tid] : 0;
    p[tid] = v; __syncthreads();
    for (int dd = 1; dd < 256; dd <<= 1) {
        int a = (tid >= dd) ? p[tid - dd] : 0;
        __syncthreads();
        p[tid] += a;
        __syncthreads();
    }
    int excl = p[tid] - v;
    if (tid < NB) { coarseOff[tid] = excl; coarseCur[tid] = excl; }
    if (tid == 0) coarseOff[NB] = E;
}

// Pass A: coarse-bucket edges. Record = (r*Ns + src)(20b) | dstLow(<=9b at bit 20).
__global__ __launch_bounds__(256) void multisplit_A(
        const int* __restrict__ dst, const int* __restrict__ src,
        const int* __restrict__ rating, int* __restrict__ coarseCur,
        unsigned* __restrict__ staged, int E, int shift, int Ns) {
    __shared__ unsigned srt[2048];
    __shared__ int sft[2048];
    __shared__ int hist[256], pfx[256], shm[256];
    const int tid = threadIdx.x;
    const int tile = blockIdx.x * 2048;
    int cnt = E - tile; if (cnt > 2048) cnt = 2048;
    hist[tid] = 0;
    __syncthreads();
    unsigned rec[8]; int bk[8];
    #pragma unroll
    for (int k = 0; k < 8; ++k) {
        int i = tile + k * 256 + tid;
        bk[k] = -1;
        if (i < E) {
            int d = dst[i], s = src[i], r = rating[i];
            bk[k] = d >> shift;
            rec[k] = (unsigned)(s + r * Ns) | ((unsigned)(d & ((1 << shift) - 1)) << 20);
            atomicAdd(&hist[bk[k]], 1);
        }
    }
    __syncthreads();
    pfx[tid] = hist[tid];
    __syncthreads();
    for (int dd = 1; dd < 256; dd <<= 1) {
        int a = (tid >= dd) ? pfx[tid - dd] : 0;
        __syncthreads();
        pfx[tid] += a;
        __syncthreads();
    }
    int h = hist[tid];
    int excl = pfx[tid] - h;
    int gb = 0;
    if (h > 0) gb = atomicAdd(&coarseCur[tid], h);
    shm[tid] = gb - excl;
    __syncthreads();
    hist[tid] = excl;          // reuse as local cursor
    __syncthreads();
    #pragma unroll
    for (int k = 0; k < 8; ++k) {
        if (bk[k] >= 0) {
            int p = atomicAdd(&hist[bk[k]], 1);
            srt[p] = rec[k];
            sft[p] = shm[bk[k]];
        }
    }
    __syncthreads();
    for (int i = tid; i < cnt; i += 256)
        staged[sft[i] + i] = srt[i];
}

// Pass B: one block per coarse bucket. LDS-stage records, local 512-slot hist
// + scan -> CSR off[] for this dst range, then in-place sorted write.
__global__ __launch_bounds__(256) void multisplit_B(
        unsigned* __restrict__ staged, const int* __restrict__ coarseOff,
        int* __restrict__ off, int N, int E, int shift) {
    __shared__ unsigned rec[16384];
    __shared__ int hist[512], pfx[512];
    const int tid = threadIdx.x;
    const int b = blockIdx.x;
    const int range = 1 << shift;
    int cbase = coarseOff[b];
    int cnt = coarseOff[b + 1] - cbase;
    if (cnt > 16384) cnt = 16384;   // safety guard (never expected)
    hist[tid] = 0; hist[tid + 256] = 0;
    __syncthreads();
    for (int i = tid; i < cnt; i += 256) {
        unsigned x = staged[cbase + i];
        rec[i] = x;
        atomicAdd(&hist[x >> 20], 1);
    }
    __syncthreads();
    pfx[tid] = hist[tid]; pfx[tid + 256] = hist[tid + 256];
    __syncthreads();
    for (int dd = 1; dd < 256; dd <<= 1) {
        int a = (tid >= dd) ? pfx[tid - dd] : 0;
        int c = (tid >= dd) ? pfx[tid + 256 - dd] : 0;
        __syncthreads();
        pfx[tid] += a; pfx[tid + 256] += c;
        __syncthreads();
    }
    int tot0 = pfx[255];
    __syncthreads();
    pfx[tid + 256] += tot0;
    __syncthreads();
    int e0 = pfx[tid] - hist[tid];
    int e1 = pfx[tid + 256] - hist[tid + 256];
    __syncthreads();
    hist[tid] = e0; hist[tid + 256] = e1;   // cursors
    int dbase = b << shift;
    if (dbase + tid < N) off[dbase + tid] = cbase + e0;
    if (range > 256 && dbase + tid + 256 < N) off[dbase + tid + 256] = cbase + e1;
    if (b == gridDim.x - 1 && tid == 0) off[N] = E;
    __syncthreads();
    for (int i = tid; i < cnt; i += 256) {
        unsigned x = rec[i];
        int p = atomicAdd(&hist[x >> 20], 1);
        staged[cbase + p] = x;
    }
}

// One-time: pack weights (bf16) into MFMA fragment order.
__global__ void prep_weights(const float* __restrict__ Wr_w, const float* __restrict__ Wr_wb,
                             const float* __restrict__ Ww, const float* __restrict__ Wwb,
                             const float* __restrict__ Vf, const float* __restrict__ Wf,
                             short* __restrict__ pWrW, short* __restrict__ pWrWB,
                             short* __restrict__ pWw, short* __restrict__ pWwb,
                             short* __restrict__ pVf, short* __restrict__ pWf) {
    int t = blockIdx.x * blockDim.x + threadIdx.x;
    const float* src; short* dst; int K; int idx;
    if      (t < 24576) { src = Wr_w;  dst = pWrW;  K = 64;  idx = t; }
    else if (t < 49152) { src = Wr_wb; dst = pWrWB; K = 64;  idx = t - 24576; }
    else if (t < 57344) { src = Ww;    dst = pWw;   K = 128; idx = t - 49152; }
    else if (t < 65536) { src = Wwb;   dst = pWwb;  K = 128; idx = t - 57344; }
    else if (t < 69632) { src = Vf;    dst = pVf;   K = 64;  idx = t - 65536; }
    else if (t < 73728) { src = Wf;    dst = pWf;   K = 64;  idx = t - 69632; }
    else return;
    int per  = 64 * K;
    int sub  = idx / per;            // r for Wr packs, 0 otherwise
    int li   = idx % per;
    int e    = li & 7;
    int lane = (li >> 3) & 63;
    int frag = li >> 9;              // t16*(K/32) + tk
    int nkt  = K >> 5;
    int t16  = frag / nkt, tk = frag % nkt;
    int row  = t16 * 16 + (lane & 15);
    int col  = tk * 32 + (lane >> 4) * 8 + e;
    dst[idx] = f2bf(src[((size_t)(sub * 64 + row)) * K + col]);
}

// Per-source-node relation transform: y[r][s] = Wr[r] @ h[s], bf16, natural
// dim order (frag-ready for both elementwise gather-sum and B-frag loads).
// One wave per 16 source nodes; 48 MFMA; shuffle-transpose C -> row stores.
__global__ __launch_bounds__(256) void pretransform(
        const unsigned short* __restrict__ h,   // [Ns][64] bf16
        const short* __restrict__ pWr,          // [6][4][2][512]
        unsigned short* __restrict__ y,         // [6][Ns][64] bf16
        int Ns) {
    const int lane = threadIdx.x & 63;
    const int m = lane & 15, q = lane >> 4;
    const int wave = (blockIdx.x * blockDim.x + threadIdx.x) >> 6;
    const int n0 = wave * 16;
    if (n0 >= Ns) return;
    int nrow = n0 + m; if (nrow > Ns - 1) nrow = Ns - 1;

    bf16x8 bB[2];
    {
        const unsigned short* ph = h + (size_t)nrow * D + q * 8;
        bB[0] = *(const bf16x8*)(ph);
        bB[1] = *(const bf16x8*)(ph + 32);
    }
    const int srcA = ((q & 1) << 5) + m;
    const int srcB = srcA + 16;
    const bool hiq = (q >> 1) != 0;

    #pragma unroll
    for (int r = 0; r < NRAT; ++r) {
        f32x4 acc[4] = {};
        #pragma unroll
        for (int it = 0; it < 4; ++it)
            #pragma unroll
            for (int kt = 0; kt < 2; ++kt) {
                bf16x8 a = *(const bf16x8*)(pWr + (((r * 4 + it) * 2 + kt) << 9) + (lane << 3));
                acc[it] = __builtin_amdgcn_mfma_f32_16x16x32_bf16(a, bB[kt], acc[it], 0, 0, 0);
            }
        uint32_t u0[4], u1[4];
        #pragma unroll
        for (int it = 0; it < 4; ++it) {
            u0[it] = pk2(acc[it][0], acc[it][1]);
            u1[it] = pk2(acc[it][2], acc[it][3]);
        }
        #pragma unroll
        for (int w = 0; w < 2; ++w) {
            uint32_t aa0 = (uint32_t)__shfl((int)u0[2*w],   srcA), bb0 = (uint32_t)__shfl((int)u0[2*w+1], srcA);
            uint32_t aa1 = (uint32_t)__shfl((int)u1[2*w],   srcA), bb1 = (uint32_t)__shfl((int)u1[2*w+1], srcA);
            uint32_t aa2 = (uint32_t)__shfl((int)u0[2*w],   srcB), bb2 = (uint32_t)__shfl((int)u0[2*w+1], srcB);
            uint32_t aa3 = (uint32_t)__shfl((int)u1[2*w],   srcB), bb3 = (uint32_t)__shfl((int)u1[2*w+1], srcB);
            FragU f;
            f.u[0] = hiq ? bb0 : aa0;
            f.u[1] = hiq ? bb1 : aa1;
            f.u[2] = hiq ? bb2 : aa2;
            f.u[3] = hiq ? bb3 : aa3;
            *(bf16x8*)(y + ((size_t)r * Ns + nrow) * D + w * 32 + q * 8) = f.v;
        }
    }
}

// One wave per dst node (lane = dim): rating-oblivious gather-mean of
// pre-transformed y rows (record low 20 bits = r*Ns+src). Single f32 acc set.
__global__ __launch_bounds__(256) void gather_mean(
        const int* __restrict__ off, const unsigned* __restrict__ packed,
        const unsigned short* __restrict__ y, unsigned short* __restrict__ hn, int N) {
    int lane = threadIdx.x & 63;
    int n = (blockIdx.x * blockDim.x + threadIdx.x) >> 6;
    if (n >= N) return;
    int b = off[n], e = off[n + 1];
    float a0 = 0.f, a1 = 0.f, a2 = 0.f, a3 = 0.f;

#define YLD(mm) __uint_as_float(((unsigned)y[((size_t)((mm) & 0xFFFFFu)) * D + lane]) << 16)

    for (int base = b; base < e; base += 64) {
        int idx = base + lane; if (idx > e - 1) idx = e - 1;
        unsigned meta = packed[idx];
        int cnt = e - base; if (cnt > 64) cnt = 64;
        int j = 0;
        for (; j + 4 <= cnt; j += 4) {
            unsigned m0 = (unsigned)__builtin_amdgcn_readlane((int)meta, j);
            unsigned m1 = (unsigned)__builtin_amdgcn_readlane((int)meta, j + 1);
            unsigned m2 = (unsigned)__builtin_amdgcn_readlane((int)meta, j + 2);
            unsigned m3 = (unsigned)__builtin_amdgcn_readlane((int)meta, j + 3);
            a0 += YLD(m0); a1 += YLD(m1); a2 += YLD(m2); a3 += YLD(m3);
        }
        for (; j < cnt; ++j) {
            unsigned mm = (unsigned)__builtin_amdgcn_readlane((int)meta, j);
            a0 += YLD(mm);
        }
    }
#undef YLD
    float inv = 1.0f / fmaxf((float)(e - b), 1.0f);
    hn[(size_t)n * D + lane] = (unsigned short)f2bf(((a0 + a1) + (a2 + a3)) * inv);
}

// Per-16-node-tile MFMA transform (one wave per tile), all-bf16 inputs:
//   GEMM2 (transposed): h2^T = relu(Wlin @ [hd|hn]^T + blin)
//   GEMM3 (normal):     out  = h2 @ W2^T + b2
__global__ __launch_bounds__(256) void transform_mfma(
        const unsigned short* __restrict__ hn,  // [N][64] bf16 (mean-scaled)
        const unsigned short* __restrict__ hd,  // [N][64] bf16
        const short* __restrict__ pWlin,  // [4][4][512]
        const float* __restrict__ blin,
        const short* __restrict__ pW2,    // [4][2][512]
        const float* __restrict__ b2,
        float* __restrict__ out, int N) {
    const int lane = threadIdx.x & 63;
    const int m = lane & 15, q = lane >> 4;
    const int wave = (blockIdx.x * blockDim.x + threadIdx.x) >> 6;
    const int n0 = wave * 16;
    if (n0 >= N) return;
    int nrow = n0 + m; if (nrow > N - 1) nrow = N - 1;

    bf16x8 bH[2], bHN[2];
    {
        const unsigned short* ph = hd + (size_t)nrow * D + q * 8;
        bH[0] = *(const bf16x8*)(ph);
        bH[1] = *(const bf16x8*)(ph + 32);
        const unsigned short* pn = hn + (size_t)nrow * D + q * 8;
        bHN[0] = *(const bf16x8*)(pn);
        bHN[1] = *(const bf16x8*)(pn + 32);
    }

    // ---- GEMM2: h2^T[o, n]
    f32x4 acc2[4] = {};
    #pragma unroll
    for (int it = 0; it < 4; ++it)
        #pragma unroll
        for (int kt = 0; kt < 4; ++kt) {
            bf16x8 a = *(const bf16x8*)(pWlin + (((it * 4) + kt) << 9) + (lane << 3));
            bf16x8 b = (kt < 2) ? bH[kt] : bHN[kt - 2];
            acc2[it] = __builtin_amdgcn_mfma_f32_16x16x32_bf16(a, b, acc2[it], 0, 0, 0);
        }

    // ---- bias + relu -> A3 frags
    const int srcA = ((q & 1) << 5) + m;
    const int srcB = srcA + 16;
    const bool hiq = (q >> 1) != 0;
    uint32_t u0[4], u1[4];
    float vbl = blin[lane];
    #pragma unroll
    for (int it = 0; it < 4; ++it) {
        float h0 = fmaxf(acc2[it][0] + __shfl(vbl, it * 16 + q * 4 + 0), 0.f);
        float h1 = fmaxf(acc2[it][1] + __shfl(vbl, it * 16 + q * 4 + 1), 0.f);
        float h2 = fmaxf(acc2[it][2] + __shfl(vbl, it * 16 + q * 4 + 2), 0.f);
        float h3 = fmaxf(acc2[it][3] + __shfl(vbl, it * 16 + q * 4 + 3), 0.f);
        u0[it] = pk2(h0, h1);
        u1[it] = pk2(h2, h3);
    }
    bf16x8 bA3[2];
    #pragma unroll
    for (int w = 0; w < 2; ++w) {
        uint32_t aa0 = (uint32_t)__shfl((int)u0[2*w],   srcA), bb0 = (uint32_t)__shfl((int)u0[2*w+1], srcA);
        uint32_t aa1 = (uint32_t)__shfl((int)u1[2*w],   srcA), bb1 = (uint32_t)__shfl((int)u1[2*w+1], srcA);
        uint32_t aa2 = (uint32_t)__shfl((int)u0[2*w],   srcB), bb2 = (uint32_t)__shfl((int)u0[2*w+1], srcB);
        uint32_t aa3 = (uint32_t)__shfl((int)u1[2*w],   srcB), bb3 = (uint32_t)__shfl((int)u1[2*w+1], srcB);
        FragU f;
        f.u[0] = hiq ? bb0 : aa0;
        f.u[1] = hiq ? bb1 : aa1;
        f.u[2] = hiq ? bb2 : aa2;
        f.u[3] = hiq ? bb3 : aa3;
        bA3[w] = f.v;
    }

    // ---- GEMM3 (normal): C3[node_row, o],  row=q*4+reg=node, col=ct*16+m=o
    f32x4 acc3[4] = {};
    #pragma unroll
    for (int ct = 0; ct < 4; ++ct)
        #pragma unroll
        for (int kt = 0; kt < 2; ++kt) {
            bf16x8 b = *(const bf16x8*)(pW2 + (((ct * 2) + kt) << 9) + (lane << 3));
            acc3[ct] = __builtin_amdgcn_mfma_f32_16x16x32_bf16(bA3[kt], b, acc3[ct], 0, 0, 0);
        }
    #pragma unroll
    for (int ct = 0; ct < 4; ++ct) {
        float bb = b2[ct * 16 + m];
        #pragma unroll
        for (int rg = 0; rg < 4; ++rg) {
            int n = n0 + q * 4 + rg;
            if (n < N) out[(size_t)n * D + ct * 16 + m] = acc3[ct][rg] + bb;
        }
    }
}

extern "C" void kernel_launch(void* const* d_in, const int* in_sizes, int n_in,
                              void* d_out, int out_size, void* d_ws, size_t ws_size,
                              hipStream_t stream) {
    const int*   user_ids   = (const int*)  d_in[0];
    const int*   item_ids   = (const int*)  d_in[1];
    const int*   gender     = (const int*)  d_in[2];
    const int*   genres     = (const int*)  d_in[3];
    const int*   edge_user  = (const int*)  d_in[4];
    const int*   edge_item  = (const int*)  d_in[5];
    const int*   rating     = (const int*)  d_in[6];
    const float* user_emb   = (const float*)d_in[7];
    const float* item_emb   = (const float*)d_in[8];
    const float* gender_emb = (const float*)d_in[9];
    const float* genre_emb  = (const float*)d_in[10];
    const float* Wr_watched   = (const float*)d_in[11];
    const float* Wr_watchedby = (const float*)d_in[12];
    const float* Ww  = (const float*)d_in[13];
    const float* bw  = (const float*)d_in[14];
    const float* Wwb = (const float*)d_in[15];
    const float* bwb = (const float*)d_in[16];
    const float* Wf  = (const float*)d_in[17];
    const float* bf  = (const float*)d_in[18];
    const float* Vf  = (const float*)d_in[19];
    const float* bv  = (const float*)d_in[20];

    const int NU = in_sizes[0];
    const int NI = in_sizes[1];
    const int E  = in_sizes[4];
    const int maxN = (NU > NI) ? NU : NI;
    const int SH_I = 8, SH_U = 9;
    const int NBI = (NI + (1 << SH_I) - 1) >> SH_I;   // <=256
    const int NBU = (NU + (1 << SH_U) - 1) >> SH_U;   // <=256

    float* out_f    = (float*)d_out;
    float* user_out = out_f;                       // [NU,64]
    float* item_out = out_f + (size_t)NU * D;      // [NI,64]

    // ws layout (bf16 first): hu, hi, hn, y[6*maxN*64], packs, ints, staged
    unsigned short* hu = (unsigned short*)d_ws;
    unsigned short* hi = hu + (size_t)NU * D;
    unsigned short* hn = hi + (size_t)NI * D;
    unsigned short* y  = hn + (size_t)maxN * D;
    size_t byteOff = (((size_t)(NU + NI + maxN) * D + (size_t)NRAT * maxN * D) * 2 + 15) & ~(size_t)15;
    short* pWrW  = (short*)((char*)d_ws + byteOff);
    short* pWrWB = pWrW  + 24576;
    short* pWw   = pWrWB + 24576;
    short* pWwb  = pWw   + 8192;
    short* pVf   = pWwb  + 8192;
    short* pWf   = pVf   + 4096;
    int* coarseCntI = (int*)(pWf + 4096);   // 256
    int* coarseCntU = coarseCntI + 256;     // 256 (memset together)
    int* coarseOffI = coarseCntU + 256;     // 257
    int* coarseOffU = coarseOffI + 257;     // 257
    int* coarseCurI = coarseOffU + 257;     // 256
    int* coarseCurU = coarseCurI + 256;     // 256
    int* offI   = coarseCurU + 256;         // NI+1
    int* offU   = offI + NI + 1;            // NU+1
    unsigned* staged = (unsigned*)(offU + NU + 1);  // E (reused by both dirs)

    // 1. node features + weight packing + coarse binning metadata
    int totalh = (NU + NI) * 16;
    build_h<<<(totalh + 255) / 256, 256, 0, stream>>>(
        user_ids, item_ids, gender, genres,
        user_emb, item_emb, gender_emb, genre_emb, hu, hi, NU, NI);
    prep_weights<<<288, 256, 0, stream>>>(Wr_watched, Wr_watchedby, Ww, Wwb, Vf, Wf,
                                          pWrW, pWrWB, pWw, pWwb, pVf, pWf);
    hipMemsetAsync(coarseCntI, 0, 512 * sizeof(int), stream);
    coarse_hist<<<512, 256, 0, stream>>>(edge_item, coarseCntI, E, SH_I);
    coarse_hist<<<512, 256, 0, stream>>>(edge_user, coarseCntU, E, SH_U);
    coarse_scan<<<1, 256, 0, stream>>>(coarseCntI, coarseOffI, coarseCurI, NBI, E);
    coarse_scan<<<1, 256, 0, stream>>>(coarseCntU, coarseOffU, coarseCurU, NBU, E);

    const int nTilesA = (E + 2047) / 2048;

    // 2. direction 'watched' (users -> items), dst = items, src = users
    multisplit_A<<<nTilesA, 256, 0, stream>>>(edge_item, edge_user, rating,
                                              coarseCurI, staged, E, SH_I, NU);
    multisplit_B<<<NBI, 256, 0, stream>>>(staged, coarseOffI, offI, NI, E, SH_I);
    {
        int waves = (NU + 15) / 16, blocks = (waves + 3) / 4;
        pretransform<<<blocks, 256, 0, stream>>>(hu, pWrW, y, NU);
    }
    gather_mean<<<(NI + 3) / 4, 256, 0, stream>>>(offI, staged, y, hn, NI);
    {
        int tiles = (NI + 15) / 16, blocks = (tiles + 3) / 4;
        transform_mfma<<<blocks, 256, 0, stream>>>(hn, hi, pWw, bw, pVf, bv,
                                                   item_out, NI);
    }

    // 3. direction 'watchedby' (items -> users), dst = users, src = items
    multisplit_A<<<nTilesA, 256, 0, stream>>>(edge_user, edge_item, rating,
                                              coarseCurU, staged, E, SH_U, NI);
    multisplit_B<<<NBU, 256, 0, stream>>>(staged, coarseOffU, offU, NU, E, SH_U);
    {
        int waves = (NI + 15) / 16, blocks = (waves + 3) / 4;
        pretransform<<<blocks, 256, 0, stream>>>(hi, pWrWB, y, NI);
    }
    gather_mean<<<(NU + 3) / 4, 256, 0, stream>>>(offU, staged, y, hn, NU);
    {
        int tiles = (NU + 15) / 16, blocks = (tiles + 3) / 4;
        transform_mfma<<<blocks, 256, 0, stream>>>(hn, hu, pWwb, bwb, pWf, bf,
                                                   user_out, NU);
    }
}

// Round 9
// 244.702 us; speedup vs baseline: 2.2947x; 1.2292x over previous
//
#include <hip/hip_runtime.h>
#include <hip/hip_bf16.h>

#define D 64
#define NRAT 6

typedef float f32x4 __attribute__((ext_vector_type(4)));
typedef short bf16x8 __attribute__((ext_vector_type(8)));

union FragU { uint32_t u[4]; bf16x8 v; };

__device__ __forceinline__ short f2bf(float f) {
    __hip_bfloat16 h = __float2bfloat16(f);
    union { __hip_bfloat16 h; short s; } c; c.h = h; return c.s;
}
__device__ __forceinline__ uint32_t pk2(float a, float b) {
    union { short s[2]; uint32_t u; } c; c.s[0] = f2bf(a); c.s[1] = f2bf(b); return c.u;
}

// hu[n] = bf16(user_emb[user_ids[n]] + gender_emb[gender[n]]);  hi analog.
// Also zeroes the 512 coarse-hist counters (folds a memset dispatch).
__global__ void build_h(const int* __restrict__ uid, const int* __restrict__ iid,
                        const int* __restrict__ gender, const int* __restrict__ genres,
                        const float* __restrict__ user_emb, const float* __restrict__ item_emb,
                        const float* __restrict__ gender_emb, const float* __restrict__ genre_emb,
                        unsigned short* __restrict__ hu, unsigned short* __restrict__ hi,
                        int* __restrict__ cntZero, int NU, int NI) {
    int t = blockIdx.x * blockDim.x + threadIdx.x;
    if (t < 512) cntZero[t] = 0;
    int total = (NU + NI) * 16;            // one float4 (4 dims) per thread
    if (t >= total) return;
    int row = t >> 4, c = t & 15;
    uint2 o;
    if (row < NU) {
        int u = uid[row], g = gender[row];
        float4 a = ((const float4*)user_emb)[(size_t)u * 16 + c];
        float4 b = ((const float4*)gender_emb)[(size_t)g * 16 + c];
        o.x = pk2(a.x + b.x, a.y + b.y); o.y = pk2(a.z + b.z, a.w + b.w);
        ((uint2*)hu)[(size_t)row * 16 + c] = o;
    } else {
        int r2 = row - NU;
        int it = iid[r2], ge = genres[r2];
        float4 a = ((const float4*)item_emb)[(size_t)it * 16 + c];
        float4 b = ((const float4*)genre_emb)[(size_t)ge * 16 + c];
        o.x = pk2(a.x + b.x, a.y + b.y); o.y = pk2(a.z + b.z, a.w + b.w);
        ((uint2*)hi)[(size_t)r2 * 16 + c] = o;
    }
}

// One pass over both edge arrays: LDS hists for items (>>8) and users (>>9).
__global__ __launch_bounds__(256) void hist_both(const int* __restrict__ edge_item,
                                                 const int* __restrict__ edge_user,
                                                 int* __restrict__ cntI, int* __restrict__ cntU,
                                                 int E) {
    __shared__ int hI[256], hU[256];
    hI[threadIdx.x] = 0; hU[threadIdx.x] = 0;
    __syncthreads();
    for (int i = blockIdx.x * blockDim.x + threadIdx.x; i < E; i += gridDim.x * blockDim.x) {
        atomicAdd(&hI[edge_item[i] >> 8], 1);
        atomicAdd(&hU[edge_user[i] >> 9], 1);
    }
    __syncthreads();
    int vi = hI[threadIdx.x], vu = hU[threadIdx.x];
    if (vi) atomicAdd(&cntI[threadIdx.x], vi);
    if (vu) atomicAdd(&cntU[threadIdx.x], vu);
}

// 2 blocks: block 0 scans items' coarse counts, block 1 users'.
__global__ __launch_bounds__(256) void scan_both(const int* __restrict__ cntI,
                                                 const int* __restrict__ cntU,
                                                 int* __restrict__ offI, int* __restrict__ offU,
                                                 int* __restrict__ curI, int* __restrict__ curU,
                                                 int NBI, int NBU, int E) {
    const int* cnt = blockIdx.x ? cntU : cntI;
    int* coarseOff  = blockIdx.x ? offU : offI;
    int* coarseCur  = blockIdx.x ? curU : curI;
    int NB          = blockIdx.x ? NBU : NBI;
    __shared__ int p[256];
    int tid = threadIdx.x;
    int v = (tid < NB) ? cnt[tid] : 0;
    p[tid] = v; __syncthreads();
    for (int dd = 1; dd < 256; dd <<= 1) {
        int a = (tid >= dd) ? p[tid - dd] : 0;
        __syncthreads();
        p[tid] += a;
        __syncthreads();
    }
    int excl = p[tid] - v;
    if (tid < NB) { coarseOff[tid] = excl; coarseCur[tid] = excl; }
    if (tid == 0) coarseOff[NB] = E;
}

// Pass A, both directions. Record = (r*Ns + src)(20b) | dstLow(<=9b at bit 20).
__global__ __launch_bounds__(256) void multisplit_A2(
        const int* __restrict__ edge_item, const int* __restrict__ edge_user,
        const int* __restrict__ rating,
        int* __restrict__ curI, int* __restrict__ curU,
        unsigned* __restrict__ staged1, unsigned* __restrict__ staged2,
        int E, int nTiles, int NU, int NI) {
    const bool dirU = blockIdx.x >= nTiles;
    const int* dst = dirU ? edge_user : edge_item;
    const int* src = dirU ? edge_item : edge_user;
    const int shift = dirU ? 9 : 8;
    const int Ns = dirU ? NI : NU;
    int* coarseCur = dirU ? curU : curI;
    unsigned* staged = dirU ? staged2 : staged1;
    const int tile = (dirU ? blockIdx.x - nTiles : blockIdx.x) * 2048;

    __shared__ unsigned srt[2048];
    __shared__ int sft[2048];
    __shared__ int hist[256], pfx[256], shm[256];
    const int tid = threadIdx.x;
    int cnt = E - tile; if (cnt > 2048) cnt = 2048;
    hist[tid] = 0;
    __syncthreads();
    unsigned rec[8]; int bk[8];
    #pragma unroll
    for (int k = 0; k < 8; ++k) {
        int i = tile + k * 256 + tid;
        bk[k] = -1;
        if (i < E) {
            int d = dst[i], s = src[i], r = rating[i];
            bk[k] = d >> shift;
            rec[k] = (unsigned)(s + r * Ns) | ((unsigned)(d & ((1 << shift) - 1)) << 20);
            atomicAdd(&hist[bk[k]], 1);
        }
    }
    __syncthreads();
    pfx[tid] = hist[tid];
    __syncthreads();
    for (int dd = 1; dd < 256; dd <<= 1) {
        int a = (tid >= dd) ? pfx[tid - dd] : 0;
        __syncthreads();
        pfx[tid] += a;
        __syncthreads();
    }
    int h = hist[tid];
    int excl = pfx[tid] - h;
    int gb = 0;
    if (h > 0) gb = atomicAdd(&coarseCur[tid], h);
    shm[tid] = gb - excl;
    __syncthreads();
    hist[tid] = excl;          // reuse as local cursor
    __syncthreads();
    #pragma unroll
    for (int k = 0; k < 8; ++k) {
        if (bk[k] >= 0) {
            int p = atomicAdd(&hist[bk[k]], 1);
            srt[p] = rec[k];
            sft[p] = shm[bk[k]];
        }
    }
    __syncthreads();
    for (int i = tid; i < cnt; i += 256)
        staged[sft[i] + i] = srt[i];
}

// Pass B, both directions: one block per coarse bucket.
__global__ __launch_bounds__(256) void multisplit_B2(
        unsigned* __restrict__ staged1, unsigned* __restrict__ staged2,
        const int* __restrict__ coarseOffI, const int* __restrict__ coarseOffU,
        int* __restrict__ offI, int* __restrict__ offU,
        int NBI, int NU, int NI, int E) {
    const bool dirU = (int)blockIdx.x >= NBI;
    unsigned* staged = dirU ? staged2 : staged1;
    const int* coarseOff = dirU ? coarseOffU : coarseOffI;
    int* off = dirU ? offU : offI;
    const int N = dirU ? NU : NI;
    const int shift = dirU ? 9 : 8;
    const int b = dirU ? blockIdx.x - NBI : blockIdx.x;
    const int nb = dirU ? (N + (1 << 9) - 1) >> 9 : NBI;

    __shared__ unsigned rec[16384];
    __shared__ int hist[512], pfx[512];
    const int tid = threadIdx.x;
    const int range = 1 << shift;
    int cbase = coarseOff[b];
    int cnt = coarseOff[b + 1] - cbase;
    if (cnt > 16384) cnt = 16384;   // safety guard (never expected)
    hist[tid] = 0; hist[tid + 256] = 0;
    __syncthreads();
    for (int i = tid; i < cnt; i += 256) {
        unsigned x = staged[cbase + i];
        rec[i] = x;
        atomicAdd(&hist[x >> 20], 1);
    }
    __syncthreads();
    pfx[tid] = hist[tid]; pfx[tid + 256] = hist[tid + 256];
    __syncthreads();
    for (int dd = 1; dd < 256; dd <<= 1) {
        int a = (tid >= dd) ? pfx[tid - dd] : 0;
        int c = (tid >= dd) ? pfx[tid + 256 - dd] : 0;
        __syncthreads();
        pfx[tid] += a; pfx[tid + 256] += c;
        __syncthreads();
    }
    int tot0 = pfx[255];
    __syncthreads();
    pfx[tid + 256] += tot0;
    __syncthreads();
    int e0 = pfx[tid] - hist[tid];
    int e1 = pfx[tid + 256] - hist[tid + 256];
    __syncthreads();
    hist[tid] = e0; hist[tid + 256] = e1;   // cursors
    int dbase = b << shift;
    if (dbase + tid < N) off[dbase + tid] = cbase + e0;
    if (range > 256 && dbase + tid + 256 < N) off[dbase + tid + 256] = cbase + e1;
    if (b == nb - 1 && tid == 0) off[N] = E;
    __syncthreads();
    for (int i = tid; i < cnt; i += 256) {
        unsigned x = rec[i];
        int p = atomicAdd(&hist[x >> 20], 1);
        staged[cbase + p] = x;
    }
}

// One-time: pack weights (bf16) into MFMA fragment order.
__global__ void prep_weights(const float* __restrict__ Wr_w, const float* __restrict__ Wr_wb,
                             const float* __restrict__ Ww, const float* __restrict__ Wwb,
                             const float* __restrict__ Vf, const float* __restrict__ Wf,
                             short* __restrict__ pWrW, short* __restrict__ pWrWB,
                             short* __restrict__ pWw, short* __restrict__ pWwb,
                             short* __restrict__ pVf, short* __restrict__ pWf) {
    int t = blockIdx.x * blockDim.x + threadIdx.x;
    const float* src; short* dst; int K; int idx;
    if      (t < 24576) { src = Wr_w;  dst = pWrW;  K = 64;  idx = t; }
    else if (t < 49152) { src = Wr_wb; dst = pWrWB; K = 64;  idx = t - 24576; }
    else if (t < 57344) { src = Ww;    dst = pWw;   K = 128; idx = t - 49152; }
    else if (t < 65536) { src = Wwb;   dst = pWwb;  K = 128; idx = t - 57344; }
    else if (t < 69632) { src = Vf;    dst = pVf;   K = 64;  idx = t - 65536; }
    else if (t < 73728) { src = Wf;    dst = pWf;   K = 64;  idx = t - 69632; }
    else return;
    int per  = 64 * K;
    int sub  = idx / per;            // r for Wr packs, 0 otherwise
    int li   = idx % per;
    int e    = li & 7;
    int lane = (li >> 3) & 63;
    int frag = li >> 9;              // t16*(K/32) + tk
    int nkt  = K >> 5;
    int t16  = frag / nkt, tk = frag % nkt;
    int row  = t16 * 16 + (lane & 15);
    int col  = tk * 32 + (lane >> 4) * 8 + e;
    dst[idx] = f2bf(src[((size_t)(sub * 64 + row)) * K + col]);
}

// Per-source-node relation transform, both directions in one launch:
// y[r][s] = Wr[r] @ h[s], bf16, natural dim order.
__global__ __launch_bounds__(256) void pretransform2(
        const unsigned short* __restrict__ hu, const unsigned short* __restrict__ hi,
        const short* __restrict__ pWrW, const short* __restrict__ pWrWB,
        unsigned short* __restrict__ y1, unsigned short* __restrict__ y2,
        int NU, int NI, int wavesU) {
    const int lane = threadIdx.x & 63;
    const int m = lane & 15, q = lane >> 4;
    int wave = (blockIdx.x * blockDim.x + threadIdx.x) >> 6;
    const bool dirI = wave >= wavesU;
    const unsigned short* h = dirI ? hi : hu;
    const short* pWr = dirI ? pWrWB : pWrW;
    unsigned short* y = dirI ? y2 : y1;
    const int Ns = dirI ? NI : NU;
    if (dirI) wave -= wavesU;
    const int n0 = wave * 16;
    if (n0 >= Ns) return;
    int nrow = n0 + m; if (nrow > Ns - 1) nrow = Ns - 1;

    bf16x8 bB[2];
    {
        const unsigned short* ph = h + (size_t)nrow * D + q * 8;
        bB[0] = *(const bf16x8*)(ph);
        bB[1] = *(const bf16x8*)(ph + 32);
    }
    const int srcA = ((q & 1) << 5) + m;
    const int srcB = srcA + 16;
    const bool hiq = (q >> 1) != 0;

    #pragma unroll
    for (int r = 0; r < NRAT; ++r) {
        f32x4 acc[4] = {};
        #pragma unroll
        for (int it = 0; it < 4; ++it)
            #pragma unroll
            for (int kt = 0; kt < 2; ++kt) {
                bf16x8 a = *(const bf16x8*)(pWr + (((r * 4 + it) * 2 + kt) << 9) + (lane << 3));
                acc[it] = __builtin_amdgcn_mfma_f32_16x16x32_bf16(a, bB[kt], acc[it], 0, 0, 0);
            }
        uint32_t u0[4], u1[4];
        #pragma unroll
        for (int it = 0; it < 4; ++it) {
            u0[it] = pk2(acc[it][0], acc[it][1]);
            u1[it] = pk2(acc[it][2], acc[it][3]);
        }
        #pragma unroll
        for (int w = 0; w < 2; ++w) {
            uint32_t aa0 = (uint32_t)__shfl((int)u0[2*w],   srcA), bb0 = (uint32_t)__shfl((int)u0[2*w+1], srcA);
            uint32_t aa1 = (uint32_t)__shfl((int)u1[2*w],   srcA), bb1 = (uint32_t)__shfl((int)u1[2*w+1], srcA);
            uint32_t aa2 = (uint32_t)__shfl((int)u0[2*w],   srcB), bb2 = (uint32_t)__shfl((int)u0[2*w+1], srcB);
            uint32_t aa3 = (uint32_t)__shfl((int)u1[2*w],   srcB), bb3 = (uint32_t)__shfl((int)u1[2*w+1], srcB);
            FragU f;
            f.u[0] = hiq ? bb0 : aa0;
            f.u[1] = hiq ? bb1 : aa1;
            f.u[2] = hiq ? bb2 : aa2;
            f.u[3] = hiq ? bb3 : aa3;
            *(bf16x8*)(y + ((size_t)r * Ns + nrow) * D + w * 32 + q * 8) = f.v;
        }
    }
}

// One wave per dst node, both directions: rating-oblivious gather-mean of
// pre-transformed y rows (record low 20 bits = r*Ns+src).
__global__ __launch_bounds__(256) void gather_both(
        const int* __restrict__ offI, const int* __restrict__ offU,
        const unsigned* __restrict__ staged1, const unsigned* __restrict__ staged2,
        const unsigned short* __restrict__ y1, const unsigned short* __restrict__ y2,
        unsigned short* __restrict__ hn1, unsigned short* __restrict__ hn2,
        int NI, int NU) {
    int lane = threadIdx.x & 63;
    int g = (blockIdx.x * blockDim.x + threadIdx.x) >> 6;
    const bool dirU = g >= NI;
    int n = dirU ? g - NI : g;
    if (dirU && n >= NU) return;
    const int* off = dirU ? offU : offI;
    const unsigned* packed = dirU ? staged2 : staged1;
    const unsigned short* y = dirU ? y2 : y1;
    unsigned short* hn = dirU ? hn2 : hn1;

    int b = off[n], e = off[n + 1];
    float a0 = 0.f, a1 = 0.f, a2 = 0.f, a3 = 0.f;

#define YLD(mm) __uint_as_float(((unsigned)y[((size_t)((mm) & 0xFFFFFu)) * D + lane]) << 16)

    for (int base = b; base < e; base += 64) {
        int idx = base + lane; if (idx > e - 1) idx = e - 1;
        unsigned meta = packed[idx];
        int cnt = e - base; if (cnt > 64) cnt = 64;
        int j = 0;
        for (; j + 4 <= cnt; j += 4) {
            unsigned m0 = (unsigned)__builtin_amdgcn_readlane((int)meta, j);
            unsigned m1 = (unsigned)__builtin_amdgcn_readlane((int)meta, j + 1);
            unsigned m2 = (unsigned)__builtin_amdgcn_readlane((int)meta, j + 2);
            unsigned m3 = (unsigned)__builtin_amdgcn_readlane((int)meta, j + 3);
            a0 += YLD(m0); a1 += YLD(m1); a2 += YLD(m2); a3 += YLD(m3);
        }
        for (; j < cnt; ++j) {
            unsigned mm = (unsigned)__builtin_amdgcn_readlane((int)meta, j);
            a0 += YLD(mm);
        }
    }
#undef YLD
    float inv = 1.0f / fmaxf((float)(e - b), 1.0f);
    hn[(size_t)n * D + lane] = (unsigned short)f2bf(((a0 + a1) + (a2 + a3)) * inv);
}

// Per-16-node-tile MFMA transform, both directions:
//   GEMM2 (transposed): h2^T = relu(Wlin @ [hd|hn]^T + blin)
//   GEMM3 (normal):     out  = h2 @ W2^T + b2
__global__ __launch_bounds__(256) void transform_both(
        const unsigned short* __restrict__ hn1, const unsigned short* __restrict__ hn2,
        const unsigned short* __restrict__ hi, const unsigned short* __restrict__ hu,
        const short* __restrict__ pWw, const short* __restrict__ pWwb,
        const float* __restrict__ bw, const float* __restrict__ bwb,
        const short* __restrict__ pVf, const short* __restrict__ pWf,
        const float* __restrict__ bv, const float* __restrict__ bf,
        float* __restrict__ item_out, float* __restrict__ user_out,
        int NI, int NU, int tilesI) {
    const int lane = threadIdx.x & 63;
    const int m = lane & 15, q = lane >> 4;
    int wave = (blockIdx.x * blockDim.x + threadIdx.x) >> 6;
    const bool dirU = wave >= tilesI;
    if (dirU) wave -= tilesI;
    const unsigned short* hn = dirU ? hn2 : hn1;
    const unsigned short* hd = dirU ? hu : hi;
    const short* pWlin = dirU ? pWwb : pWw;
    const float* blin  = dirU ? bwb : bw;
    const short* pW2   = dirU ? pWf : pVf;
    const float* b2    = dirU ? bf : bv;
    float* out = dirU ? user_out : item_out;
    const int N = dirU ? NU : NI;
    const int n0 = wave * 16;
    if (n0 >= N) return;
    int nrow = n0 + m; if (nrow > N - 1) nrow = N - 1;

    bf16x8 bH[2], bHN[2];
    {
        const unsigned short* ph = hd + (size_t)nrow * D + q * 8;
        bH[0] = *(const bf16x8*)(ph);
        bH[1] = *(const bf16x8*)(ph + 32);
        const unsigned short* pn = hn + (size_t)nrow * D + q * 8;
        bHN[0] = *(const bf16x8*)(pn);
        bHN[1] = *(const bf16x8*)(pn + 32);
    }

    // ---- GEMM2: h2^T[o, n]
    f32x4 acc2[4] = {};
    #pragma unroll
    for (int it = 0; it < 4; ++it)
        #pragma unroll
        for (int kt = 0; kt < 4; ++kt) {
            bf16x8 a = *(const bf16x8*)(pWlin + (((it * 4) + kt) << 9) + (lane << 3));
            bf16x8 b = (kt < 2) ? bH[kt] : bHN[kt - 2];
            acc2[it] = __builtin_amdgcn_mfma_f32_16x16x32_bf16(a, b, acc2[it], 0, 0, 0);
        }

    // ---- bias + relu -> A3 frags
    const int srcA = ((q & 1) << 5) + m;
    const int srcB = srcA + 16;
    const bool hiq = (q >> 1) != 0;
    uint32_t u0[4], u1[4];
    float vbl = blin[lane];
    #pragma unroll
    for (int it = 0; it < 4; ++it) {
        float h0 = fmaxf(acc2[it][0] + __shfl(vbl, it * 16 + q * 4 + 0), 0.f);
        float h1 = fmaxf(acc2[it][1] + __shfl(vbl, it * 16 + q * 4 + 1), 0.f);
        float h2 = fmaxf(acc2[it][2] + __shfl(vbl, it * 16 + q * 4 + 2), 0.f);
        float h3 = fmaxf(acc2[it][3] + __shfl(vbl, it * 16 + q * 4 + 3), 0.f);
        u0[it] = pk2(h0, h1);
        u1[it] = pk2(h2, h3);
    }
    bf16x8 bA3[2];
    #pragma unroll
    for (int w = 0; w < 2; ++w) {
        uint32_t aa0 = (uint32_t)__shfl((int)u0[2*w],   srcA), bb0 = (uint32_t)__shfl((int)u0[2*w+1], srcA);
        uint32_t aa1 = (uint32_t)__shfl((int)u1[2*w],   srcA), bb1 = (uint32_t)__shfl((int)u1[2*w+1], srcA);
        uint32_t aa2 = (uint32_t)__shfl((int)u0[2*w],   srcB), bb2 = (uint32_t)__shfl((int)u0[2*w+1], srcB);
        uint32_t aa3 = (uint32_t)__shfl((int)u1[2*w],   srcB), bb3 = (uint32_t)__shfl((int)u1[2*w+1], srcB);
        FragU f;
        f.u[0] = hiq ? bb0 : aa0;
        f.u[1] = hiq ? bb1 : aa1;
        f.u[2] = hiq ? bb2 : aa2;
        f.u[3] = hiq ? bb3 : aa3;
        bA3[w] = f.v;
    }

    // ---- GEMM3 (normal): C3[node_row, o],  row=q*4+reg=node, col=ct*16+m=o
    f32x4 acc3[4] = {};
    #pragma unroll
    for (int ct = 0; ct < 4; ++ct)
        #pragma unroll
        for (int kt = 0; kt < 2; ++kt) {
            bf16x8 b = *(const bf16x8*)(pW2 + (((ct * 2) + kt) << 9) + (lane << 3));
            acc3[ct] = __builtin_amdgcn_mfma_f32_16x16x32_bf16(bA3[kt], b, acc3[ct], 0, 0, 0);
        }
    #pragma unroll
    for (int ct = 0; ct < 4; ++ct) {
        float bb = b2[ct * 16 + m];
        #pragma unroll
        for (int rg = 0; rg < 4; ++rg) {
            int n = n0 + q * 4 + rg;
            if (n < N) out[(size_t)n * D + ct * 16 + m] = acc3[ct][rg] + bb;
        }
    }
}

extern "C" void kernel_launch(void* const* d_in, const int* in_sizes, int n_in,
                              void* d_out, int out_size, void* d_ws, size_t ws_size,
                              hipStream_t stream) {
    const int*   user_ids   = (const int*)  d_in[0];
    const int*   item_ids   = (const int*)  d_in[1];
    const int*   gender     = (const int*)  d_in[2];
    const int*   genres     = (const int*)  d_in[3];
    const int*   edge_user  = (const int*)  d_in[4];
    const int*   edge_item  = (const int*)  d_in[5];
    const int*   rating     = (const int*)  d_in[6];
    const float* user_emb   = (const float*)d_in[7];
    const float* item_emb   = (const float*)d_in[8];
    const float* gender_emb = (const float*)d_in[9];
    const float* genre_emb  = (const float*)d_in[10];
    const float* Wr_watched   = (const float*)d_in[11];
    const float* Wr_watchedby = (const float*)d_in[12];
    const float* Ww  = (const float*)d_in[13];
    const float* bw  = (const float*)d_in[14];
    const float* Wwb = (const float*)d_in[15];
    const float* bwb = (const float*)d_in[16];
    const float* Wf  = (const float*)d_in[17];
    const float* bf  = (const float*)d_in[18];
    const float* Vf  = (const float*)d_in[19];
    const float* bv  = (const float*)d_in[20];

    const int NU = in_sizes[0];
    const int NI = in_sizes[1];
    const int E  = in_sizes[4];
    const int NBI = (NI + 255) >> 8;   // <=256 coarse buckets (shift 8)
    const int NBU = (NU + 511) >> 9;   // <=256 coarse buckets (shift 9)

    float* out_f    = (float*)d_out;
    float* user_out = out_f;                       // [NU,64]
    float* item_out = out_f + (size_t)NU * D;      // [NI,64]

    // ws layout (bf16 first): hu, hi, hn1, hn2, y1, y2, packs, ints, staged x2
    unsigned short* hu  = (unsigned short*)d_ws;
    unsigned short* hi  = hu  + (size_t)NU * D;
    unsigned short* hn1 = hi  + (size_t)NI * D;            // items' agg
    unsigned short* hn2 = hn1 + (size_t)NI * D;            // users' agg
    unsigned short* y1  = hn2 + (size_t)NU * D;            // [6][NU][64]
    unsigned short* y2  = y1  + (size_t)NRAT * NU * D;     // [6][NI][64]
    size_t bfElems = (size_t)(2 * NU + 2 * NI) * D + (size_t)NRAT * (NU + NI) * D;
    size_t byteOff = (bfElems * 2 + 15) & ~(size_t)15;
    short* pWrW  = (short*)((char*)d_ws + byteOff);
    short* pWrWB = pWrW  + 24576;
    short* pWw   = pWrWB + 24576;
    short* pWwb  = pWw   + 8192;
    short* pVf   = pWwb  + 8192;
    short* pWf   = pVf   + 4096;
    int* coarseCntI = (int*)(pWf + 4096);   // 256
    int* coarseCntU = coarseCntI + 256;     // 256 (zeroed by build_h)
    int* coarseOffI = coarseCntU + 256;     // 257
    int* coarseOffU = coarseOffI + 257;     // 257
    int* coarseCurI = coarseOffU + 257;     // 256
    int* coarseCurU = coarseCurI + 256;     // 256
    int* offI   = coarseCurU + 256;         // NI+1
    int* offU   = offI + NI + 1;            // NU+1
    unsigned* staged1 = (unsigned*)(offU + NU + 1);  // E
    unsigned* staged2 = staged1 + E;                 // E

    // 1. node features (+ counter zeroing) + weight packing + binning metadata
    int totalh = (NU + NI) * 16;
    build_h<<<(totalh + 255) / 256, 256, 0, stream>>>(
        user_ids, item_ids, gender, genres,
        user_emb, item_emb, gender_emb, genre_emb, hu, hi, coarseCntI, NU, NI);
    prep_weights<<<288, 256, 0, stream>>>(Wr_watched, Wr_watchedby, Ww, Wwb, Vf, Wf,
                                          pWrW, pWrWB, pWw, pWwb, pVf, pWf);
    hist_both<<<512, 256, 0, stream>>>(edge_item, edge_user, coarseCntI, coarseCntU, E);
    scan_both<<<2, 256, 0, stream>>>(coarseCntI, coarseCntU, coarseOffI, coarseOffU,
                                     coarseCurI, coarseCurU, NBI, NBU, E);

    // 2. sort both directions
    const int nTilesA = (E + 2047) / 2048;
    multisplit_A2<<<2 * nTilesA, 256, 0, stream>>>(edge_item, edge_user, rating,
                                                   coarseCurI, coarseCurU,
                                                   staged1, staged2, E, nTilesA, NU, NI);
    multisplit_B2<<<NBI + NBU, 256, 0, stream>>>(staged1, staged2, coarseOffI, coarseOffU,
                                                 offI, offU, NBI, NU, NI, E);

    // 3. pretransform both, gather both, transform both
    {
        int wavesU = (NU + 15) / 16, wavesI = (NI + 15) / 16;
        int blocks = (wavesU + wavesI + 3) / 4;
        pretransform2<<<blocks, 256, 0, stream>>>(hu, hi, pWrW, pWrWB, y1, y2, NU, NI, wavesU);
    }
    gather_both<<<(NI + NU + 3) / 4, 256, 0, stream>>>(offI, offU, staged1, staged2,
                                                       y1, y2, hn1, hn2, NI, NU);
    {
        int tilesI = (NI + 15) / 16, tilesU = (NU + 15) / 16;
        int blocks = (tilesI + tilesU + 3) / 4;
        transform_both<<<blocks, 256, 0, stream>>>(hn1, hn2, hi, hu, pWw, pWwb, bw, bwb,
                                                   pVf, pWf, bv, bf, item_out, user_out,
                                                   NI, NU, tilesI);
    }
}